// Round 5
// baseline (505.480 us; speedup 1.0000x reference)
//
#include <hip/hip_runtime.h>
#include <cmath>

typedef unsigned int u32;
typedef unsigned long long u64;
typedef unsigned char u8;
typedef float f32x4 __attribute__((ext_vector_type(4)));

// Marching-tets tables from the reference
__constant__ signed char c_tri[16][6] = {
    {-1,-1,-1,-1,-1,-1},
    { 1, 0, 2,-1,-1,-1},
    { 4, 0, 3,-1,-1,-1},
    { 1, 4, 2, 1, 3, 4},
    { 3, 1, 5,-1,-1,-1},
    { 2, 3, 0, 2, 5, 3},
    { 1, 4, 0, 1, 5, 4},
    { 4, 2, 5,-1,-1,-1},
    { 4, 5, 2,-1,-1,-1},
    { 4, 1, 0, 4, 5, 1},
    { 3, 2, 0, 3, 5, 2},
    { 1, 3, 5,-1,-1,-1},
    { 4, 1, 2, 4, 3, 1},
    { 3, 0, 4,-1,-1,-1},
    { 2, 0, 1,-1,-1,-1},
    {-1,-1,-1,-1,-1,-1}};
__constant__ signed char c_ntri[16] = {0,1,1,2,1,2,2,1,1,2,2,1,2,1,1,0};
__constant__ signed char c_edge_p[6] = {0,0,0,1,1,2};
__constant__ signed char c_edge_q[6] = {1,2,3,2,3,3};
// 6-tet decomposition of a cube around the 0-7 diagonal (corner n: bit0=dx,bit1=dy,bit2=dz)
__constant__ u8 c_six[6][4] = {{0,5,1,7},{0,1,3,7},{0,3,2,7},{0,2,6,7},{0,6,4,7},{0,4,5,7}};

// ---- zero the totals slot (d_ws is poisoned, not re-zeroed between replays)
__global__ void k_zero(u32* __restrict__ totals) {
    if (threadIdx.x < 16) totals[threadIdx.x] = 0;
}

// ---- fused pass: vertex crossing mask + occ bit + cube tet counts + totals
__global__ void k_main(const float* __restrict__ sdf, u8* __restrict__ vmask,
                       u32* __restrict__ vbsums, u32* __restrict__ cbsums,
                       u32* __restrict__ totals, int Nv, int V, int G) {
    int v = blockIdx.x * 256 + threadIdx.x;
    u32 cnt = 0, pack = 0;
    if (v < Nv) {
        int x = v % V;
        int t = v / V;
        int y = t % V;
        int z = t / V;
        const int V2 = V * V;
        float s0 = sdf[v];
        bool occ0 = s0 > 0.0f;
        bool bx = x < G, by = y < G, bz = z < G;
        int  d[7]  = {1, V, V + 1, V2, V2 + 1, V2 + V, V2 + V + 1};
        bool ok[7] = {bx, by, bx && by, bz, bx && bz, by && bz, bx && by && bz};
        u32 m = 0;
        u32 occ8 = occ0 ? 1u : 0u;
#pragma unroll
        for (int k = 0; k < 7; ++k) {
            if (ok[k]) {
                bool o1 = sdf[v + d[k]] > 0.0f;
                occ8 |= (u32)o1 << (k + 1);
                if (o1 != occ0) m |= (1u << k);
            }
        }
        vmask[v] = (u8)(m | (occ0 ? 0x80u : 0u));
        cnt = __popc(m);
        if (bx && by && bz) {
            u32 c1 = 0, c2 = 0;
#pragma unroll
            for (int w = 0; w < 6; ++w) {
                int ti = ((occ8 >> c_six[w][0]) & 1) | (((occ8 >> c_six[w][1]) & 1) << 1) |
                         (((occ8 >> c_six[w][2]) & 1) << 2) | (((occ8 >> c_six[w][3]) & 1) << 3);
                int nt = c_ntri[ti];
                c1 += (nt == 1);
                c2 += (nt == 2);
            }
            pack = c1 | (c2 << 16);
        }
    }
    int lane = threadIdx.x & 63, wid = threadIdx.x >> 6;
    u32 sc = cnt, sp = pack;
#pragma unroll
    for (int o = 32; o > 0; o >>= 1) {
        sc += __shfl_down(sc, o, 64);
        sp += __shfl_down(sp, o, 64);
    }
    __shared__ u32 wc[4], wp[4];
    if (lane == 0) { wc[wid] = sc; wp[wid] = sp; }
    __syncthreads();
    if (threadIdx.x == 0) {
        u32 tc = wc[0] + wc[1] + wc[2] + wc[3];
        u32 tp = wp[0] + wp[1] + wp[2] + wp[3];
        vbsums[blockIdx.x] = tc;
        cbsums[blockIdx.x] = tp;
        atomicAdd(&totals[0], tc);
        atomicAdd(&totals[1], tp & 0xFFFFu);
        atomicAdd(&totals[2], tp >> 16);
    }
}

// ---- uvs element helper (head/tail scalar path) ---------------------------
__device__ inline float uv_elem(long long e, int Nuv, double invN, double step_d,
                                float pad, float last) {
    long long p = e >> 3;
    int i = (int)((double)p * invN);
    int j = (int)(p - (long long)i * Nuv);
    if (j >= Nuv) { j -= Nuv; ++i; }
    int r = (int)(e & 7);
    int c = r >> 1;
    if ((r & 1) == 0) {
        float tx = (j == Nuv - 1) ? last : (float)((double)j * step_d);
        return tx + ((c == 1 || c == 2) ? pad : 0.0f);
    }
    float ty = (i == Nuv - 1) ? last : (float)((double)i * step_d);
    return ty + ((c >= 2) ? pad : 0.0f);
}

// ---- block 0: scan vbsums; block 1: scan cbsums->coffs; rest: write uvs ---
__global__ void k_scan_uvs(u32* __restrict__ vbsums, int nV,
                           u32* __restrict__ cbsums, u64* __restrict__ coffs, int nC,
                           const u32* __restrict__ totals, float* __restrict__ out,
                           int Nuv, double invN, double step_d, float pad, float last,
                           long long npts2) {
    int tid = threadIdx.x;
    int lane = tid & 63, wid = tid >> 6;
    if (blockIdx.x == 0) {
        // exclusive scan of vbsums in place (256 thr x 4 elems/iter)
        __shared__ u32 wred[4];
        __shared__ u32 s_carry;
        if (tid == 0) s_carry = 0;
        __syncthreads();
        for (int start = 0; start < nV; start += 1024) {
            int i0 = start + tid * 4;
            u32 a0 = (i0     < nV) ? vbsums[i0]     : 0u;
            u32 a1 = (i0 + 1 < nV) ? vbsums[i0 + 1] : 0u;
            u32 a2 = (i0 + 2 < nV) ? vbsums[i0 + 2] : 0u;
            u32 a3 = (i0 + 3 < nV) ? vbsums[i0 + 3] : 0u;
            u32 t1 = a0 + a1, t2 = t1 + a2, t3 = t2 + a3;
            u32 v = t3;
#pragma unroll
            for (int o = 1; o < 64; o <<= 1) {
                u32 t = __shfl_up(v, o, 64);
                if (lane >= o) v += t;
            }
            if (lane == 63) wred[wid] = v;
            __syncthreads();
            u32 wb = 0;
#pragma unroll
            for (int k = 0; k < 4; ++k)
                if (k < wid) wb += wred[k];
            u32 carry = s_carry;
            u32 eb = carry + wb + v - t3;
            if (i0     < nV) vbsums[i0]     = eb;
            if (i0 + 1 < nV) vbsums[i0 + 1] = eb + a0;
            if (i0 + 2 < nV) vbsums[i0 + 2] = eb + t1;
            if (i0 + 3 < nV) vbsums[i0 + 3] = eb + t2;
            __syncthreads();
            if (tid == 0) s_carry = carry + wred[0] + wred[1] + wred[2] + wred[3];
            __syncthreads();
        }
        return;
    }
    if (blockIdx.x == 1) {
        // exclusive scan of packed cbsums -> u64 coffs
        __shared__ u64 wred[4];
        __shared__ u64 s_carry;
        if (tid == 0) s_carry = 0;
        __syncthreads();
        for (int start = 0; start < nC; start += 1024) {
            int i0 = start + tid * 4;
            u32 r0 = (i0     < nC) ? cbsums[i0]     : 0u;
            u32 r1 = (i0 + 1 < nC) ? cbsums[i0 + 1] : 0u;
            u32 r2 = (i0 + 2 < nC) ? cbsums[i0 + 2] : 0u;
            u32 r3 = (i0 + 3 < nC) ? cbsums[i0 + 3] : 0u;
            u64 a0 = (u64)(r0 & 0xFFFFu) | ((u64)(r0 >> 16) << 32);
            u64 a1 = (u64)(r1 & 0xFFFFu) | ((u64)(r1 >> 16) << 32);
            u64 a2 = (u64)(r2 & 0xFFFFu) | ((u64)(r2 >> 16) << 32);
            u64 a3 = (u64)(r3 & 0xFFFFu) | ((u64)(r3 >> 16) << 32);
            u64 t1 = a0 + a1, t2 = t1 + a2, t3 = t2 + a3;
            u64 v = t3;
#pragma unroll
            for (int o = 1; o < 64; o <<= 1) {
                u64 t = __shfl_up(v, o, 64);
                if (lane >= o) v += t;
            }
            if (lane == 63) wred[wid] = v;
            __syncthreads();
            u64 wb = 0;
#pragma unroll
            for (int k = 0; k < 4; ++k)
                if (k < wid) wb += wred[k];
            u64 carry = s_carry;
            u64 eb = carry + wb + v - t3;
            if (i0     < nC) coffs[i0]     = eb;
            if (i0 + 1 < nC) coffs[i0 + 1] = eb + a0;
            if (i0 + 2 < nC) coffs[i0 + 2] = eb + t1;
            if (i0 + 3 < nC) coffs[i0 + 3] = eb + t2;
            __syncthreads();
            if (tid == 0) s_carry = carry + wred[0] + wred[1] + wred[2] + wred[3];
            __syncthreads();
        }
        return;
    }

    // ---- uvs writer: one uv quad (8 elements, 2x16B NT stores) per thread
    u32 E = totals[0], Tm1 = totals[1], Tm2 = totals[2];
    u64 base = 3ull * E + 3ull * ((u64)Tm1 + 2ull * (u64)Tm2);
    float* uvs = out + base;
    int a = (int)((4 - (base & 3)) & 3);  // first 16B-aligned element
    long long nthr = (npts2 - a) >> 3;
    long long t = (long long)(blockIdx.x - 2) * 256 + tid;
    if (t < nthr) {
        // quad p0 = t, possibly spilling 'a' elements into quad t+1
        int i = (int)((double)t * invN);
        int j = (int)(t - (long long)i * Nuv);
        if (j >= Nuv) { j -= Nuv; ++i; }
        float tx  = (j == Nuv - 1) ? last : (float)((double)j * step_d);
        float ty  = (i == Nuv - 1) ? last : (float)((double)i * step_d);
        float txp = tx + pad, typ = ty + pad;
        int j1 = j + 1, i1 = i;
        if (j1 == Nuv) { j1 = 0; ++i1; }
        float tx1  = (j1 == Nuv - 1) ? last : (float)((double)j1 * step_d);
        float ty1  = (i1 == Nuv - 1) ? last : (float)((double)i1 * step_d);
        float txp1 = tx1 + pad, typ1 = ty1 + pad;
        // quad pattern: [tx,ty,txp,ty,txp,typ,tx,typ]
        f32x4 s0, s1;
        switch (a) {
            case 0:  s0 = (f32x4){tx,  ty,  txp, ty };  s1 = (f32x4){txp, typ, tx,  typ};  break;
            case 1:  s0 = (f32x4){ty,  txp, ty,  txp};  s1 = (f32x4){typ, tx,  typ, tx1};  break;
            case 2:  s0 = (f32x4){txp, ty,  txp, typ};  s1 = (f32x4){tx,  typ, tx1, ty1};  break;
            default: s0 = (f32x4){ty,  txp, typ, tx };  s1 = (f32x4){typ, tx1, ty1, txp1}; break;
        }
        long long g0 = (long long)a + 8 * t;
        __builtin_nontemporal_store(s0, (f32x4*)(uvs + g0));
        __builtin_nontemporal_store(s1, (f32x4*)(uvs + g0 + 4));
    } else if (t == nthr) {
        for (long long e = 0; e < a; ++e)
            uvs[e] = uv_elem(e, Nuv, invN, step_d, pad, last);
        for (long long e = (long long)a + 8 * nthr; e < npts2; ++e)
            uvs[e] = uv_elem(e, Nuv, invN, step_d, pad, last);
    }
}

// ---- vbase materialize + crossing-vertex interpolation (fused) ------------
__global__ void k_vbase_verts(const u8* __restrict__ vmask, const u32* __restrict__ vbsums,
                              u32* __restrict__ vbase, const float* __restrict__ sdf,
                              float* __restrict__ out, int Nv, int V, float h) {
    int v = blockIdx.x * 256 + threadIdx.x;
    u32 m = (v < Nv) ? (u32)(vmask[v] & 0x7Fu) : 0u;
    u32 cnt = __popc(m);
    int lane = threadIdx.x & 63, wid = threadIdx.x >> 6;
    u32 s = cnt;
#pragma unroll
    for (int o = 1; o < 64; o <<= 1) {
        u32 t = __shfl_up(s, o, 64);
        if (lane >= o) s += t;
    }
    __shared__ u32 wsum[4];
    if (lane == 63) wsum[wid] = s;
    __syncthreads();
    u32 wb = 0;
#pragma unroll
    for (int k = 0; k < 4; ++k)
        if (k < wid) wb += wsum[k];
    u32 base = vbsums[blockIdx.x] + wb + s - cnt;
    if (v < Nv) vbase[v] = base;
    if (!m) return;

    int x = v % V;
    int t2 = v / V;
    int y = t2 % V;
    int z = t2 / V;
    const int V2 = V * V;
    const int d[7]  = {1, V, V + 1, V2, V2 + 1, V2 + V, V2 + V + 1};
    const int dx[7] = {1, 0, 1, 0, 1, 0, 1};
    const int dy[7] = {0, 1, 1, 0, 0, 1, 1};
    const int dz[7] = {0, 0, 0, 1, 1, 1, 1};
    float px = -1.0f + x * h, py = -1.0f + y * h, pz = -1.0f + z * h;
    float s0 = sdf[v];
    u32 r = base;
#pragma unroll
    for (int k = 0; k < 7; ++k) {
        if (m & (1u << k)) {
            float s1 = sdf[v + d[k]];
            float denom = s0 - s1;
            float w0 = -s1 / denom;
            float w1 = s0 / denom;
            out[3ull * r + 0] = px * w0 + (px + dx[k] * h) * w1;
            out[3ull * r + 1] = py * w0 + (py + dy[k] * h) * w1;
            out[3ull * r + 2] = pz * w0 + (pz + dz[k] * h) * w1;
            r++;
        }
    }
}

// ---- faces + uv_idx, vertex-indexed, procedural connectivity --------------
__global__ void k_facesuv(const u8* __restrict__ vmask, const u32* __restrict__ vbase,
                          const u64* __restrict__ coffs, const u32* __restrict__ totals,
                          float* __restrict__ out, int Nv, int G, int V, long long npts2) {
    int v = blockIdx.x * 256 + threadIdx.x;
    const int V2 = V * V;
    u32 pack = 0, occ8 = 0;
    int x = 0, y = 0, z = 0;
    bool interior = false;
    if (v < Nv) {
        x = v % V;
        int t = v / V;
        y = t % V;
        z = t / V;
        interior = (x < G) && (y < G) && (z < G);
    }
    const int off[8] = {0, 1, V, V + 1, V2, V2 + 1, V2 + V, V2 + V + 1};
    if (interior) {
#pragma unroll
        for (int n = 0; n < 8; ++n) occ8 |= (u32)(vmask[v + off[n]] >> 7) << n;
        u32 c1 = 0, c2 = 0;
#pragma unroll
        for (int w = 0; w < 6; ++w) {
            int ti = ((occ8 >> c_six[w][0]) & 1) | (((occ8 >> c_six[w][1]) & 1) << 1) |
                     (((occ8 >> c_six[w][2]) & 1) << 2) | (((occ8 >> c_six[w][3]) & 1) << 3);
            int nt = c_ntri[ti];
            c1 += (nt == 1);
            c2 += (nt == 2);
        }
        pack = c1 | (c2 << 16);
    }
    int lane = threadIdx.x & 63, wid = threadIdx.x >> 6;
    u32 s = pack;
#pragma unroll
    for (int o = 1; o < 64; o <<= 1) {
        u32 t = __shfl_up(s, o, 64);
        if (lane >= o) s += t;
    }
    __shared__ u32 wsum[4];
    if (lane == 63) wsum[wid] = s;
    __syncthreads();
    u32 wb = 0;
#pragma unroll
    for (int k = 0; k < 4; ++k)
        if (k < wid) wb += wsum[k];
    u32 excl = wb + s - pack;
    if (!interior || pack == 0) return;

    u64 bo = coffs[blockIdx.x];
    u32 m1pos = (u32)(bo & 0xFFFFFFFFull) + (excl & 0xFFFFu);
    u32 m2pos = (u32)(bo >> 32) + (excl >> 16);
    u32 E = totals[0], Tm1 = totals[1], Tm2 = totals[2];
    u64 T = (u64)Tm1 + 2ull * (u64)Tm2;
    float* faces = out + 3ull * E;
    float* uvidx = out + 3ull * E + 3ull * T + (u64)npts2;
    int ci = (z * G + y) * G + x;

#pragma unroll
    for (int w = 0; w < 6; ++w) {
        int ti = ((occ8 >> c_six[w][0]) & 1) | (((occ8 >> c_six[w][1]) & 1) << 1) |
                 (((occ8 >> c_six[w][2]) & 1) << 2) | (((occ8 >> c_six[w][3]) & 1) << 3);
        int nt = c_ntri[ti];
        if (!nt) continue;
        int t = ci * 6 + w;
        for (int tri = 0; tri < nt; ++tri) {
            u64 r = (nt == 1) ? (u64)m1pos : ((u64)Tm1 + 2ull * (u64)m2pos + (u64)tri);
#pragma unroll
            for (int cidx = 0; cidx < 3; ++cidx) {
                int e = c_tri[ti][3 * tri + cidx];
                int np_ = c_six[w][(int)c_edge_p[e]];
                int nq_ = c_six[w][(int)c_edge_q[e]];
                int lo = np_ < nq_ ? np_ : nq_;
                int k = (np_ ^ nq_) - 1;  // corners form a bit-subset chain
                int lonode = v + off[lo];
                u32 vi = vbase[lonode] +
                         (u32)__popc((u32)(vmask[lonode] & 0x7Fu) & ((1u << k) - 1u));
                faces[3ull * r + cidx] = (float)vi;
            }
            uvidx[3ull * r + 0] = (float)(4 * t);
            uvidx[3ull * r + 1] = (float)(4 * t + tri + 1);
            uvidx[3ull * r + 2] = (float)(4 * t + tri + 2);
        }
        if (nt == 1) m1pos++;
        else m2pos++;
    }
}

extern "C" void kernel_launch(void* const* d_in, const int* in_sizes, int n_in,
                              void* d_out, int out_size, void* d_ws, size_t ws_size,
                              hipStream_t stream) {
    const float* sdf = (const float*)d_in[1];
    int Nv = in_sizes[1];
    int F = in_sizes[2] / 4;

    int V = 1;
    while ((long long)V * V * V < (long long)Nv) V++;
    int G = V - 1;

    long long half = (2ll * (long long)F + 1) / 2;
    int Nuv = (int)std::sqrt((double)half);
    while ((long long)Nuv * Nuv < half) Nuv++;
    while (Nuv > 1 && (long long)(Nuv - 1) * (Nuv - 1) >= half) Nuv--;

    int nbV = (Nv + 255) / 256;
    long long npts2 = 2ll * 4ll * (long long)Nuv * (long long)Nuv;

    double invN = 1.0 / (double)Nuv;
    double step_d = (1.0 - invN) / (double)(Nuv - 1);
    float pad = (float)(0.9 * invN);
    float last = (float)(1.0 - invN);

    char* ws = (char*)d_ws;
    size_t off = 0;
    auto walloc = [&](size_t bytes) -> void* {
        void* p = ws + off;
        off = (off + bytes + 255) & ~(size_t)255;
        return p;
    };
    u32* totals = (u32*)walloc(64);
    u32* vbsums = (u32*)walloc(sizeof(u32) * (size_t)nbV);
    u32* cbsums = (u32*)walloc(sizeof(u32) * (size_t)nbV);
    u64* coffs  = (u64*)walloc(sizeof(u64) * (size_t)nbV);
    u8*  vmask  = (u8*)walloc((size_t)Nv);
    u32* vbase  = (u32*)walloc(sizeof(u32) * (size_t)Nv);
    (void)ws_size;

    float* out = (float*)d_out;
    float h = 2.0f / (float)G;

    long long nthrU = npts2 / 8 + 1;          // worst-case (a=0) + head/tail thread
    int nbU = (int)((nthrU + 255) / 256) + 2; // +2 scan blocks

    hipLaunchKernelGGL(k_zero, dim3(1), dim3(64), 0, stream, totals);
    hipLaunchKernelGGL(k_main, dim3(nbV), dim3(256), 0, stream, sdf, vmask, vbsums, cbsums,
                       totals, Nv, V, G);
    hipLaunchKernelGGL(k_scan_uvs, dim3(nbU), dim3(256), 0, stream, vbsums, nbV, cbsums, coffs,
                       nbV, totals, out, Nuv, invN, step_d, pad, last, npts2);
    hipLaunchKernelGGL(k_vbase_verts, dim3(nbV), dim3(256), 0, stream, vmask, vbsums, vbase,
                       sdf, out, Nv, V, h);
    hipLaunchKernelGGL(k_facesuv, dim3(nbV), dim3(256), 0, stream, vmask, vbase, coffs, totals,
                       out, Nv, G, V, npts2);
}

// Round 7
// 238.638 us; speedup vs baseline: 2.1182x; 2.1182x over previous
//
#include <hip/hip_runtime.h>
#include <cmath>

typedef unsigned int u32;
typedef unsigned long long u64;
typedef unsigned char u8;
typedef float f32x4 __attribute__((ext_vector_type(4)));

// Marching-tets tables from the reference
__constant__ signed char c_tri[16][6] = {
    {-1,-1,-1,-1,-1,-1},
    { 1, 0, 2,-1,-1,-1},
    { 4, 0, 3,-1,-1,-1},
    { 1, 4, 2, 1, 3, 4},
    { 3, 1, 5,-1,-1,-1},
    { 2, 3, 0, 2, 5, 3},
    { 1, 4, 0, 1, 5, 4},
    { 4, 2, 5,-1,-1,-1},
    { 4, 5, 2,-1,-1,-1},
    { 4, 1, 0, 4, 5, 1},
    { 3, 2, 0, 3, 5, 2},
    { 1, 3, 5,-1,-1,-1},
    { 4, 1, 2, 4, 3, 1},
    { 3, 0, 4,-1,-1,-1},
    { 2, 0, 1,-1,-1,-1},
    {-1,-1,-1,-1,-1,-1}};
__constant__ signed char c_ntri[16] = {0,1,1,2,1,2,2,1,1,2,2,1,2,1,1,0};
__constant__ signed char c_edge_p[6] = {0,0,0,1,1,2};
__constant__ signed char c_edge_q[6] = {1,2,3,2,3,3};
// 6-tet decomposition of a cube around the 0-7 diagonal (corner n: bit0=dx,bit1=dy,bit2=dz)
__constant__ u8 c_six[6][4] = {{0,5,1,7},{0,1,3,7},{0,3,2,7},{0,2,6,7},{0,6,4,7},{0,4,5,7}};

// ---- fused pass: vertex crossing mask + occ bit + cube tet counts ---------
// NO grand-total atomics (round-5 lesson: 25K same-line cross-XCD atomics
// serialized for ~250us). Totals come from the scan kernel instead.
__global__ void k_main(const float* __restrict__ sdf, u8* __restrict__ vmask,
                       u32* __restrict__ vbsums, u32* __restrict__ cbsums,
                       int Nv, int V, int G) {
    int v = blockIdx.x * 256 + threadIdx.x;
    u32 cnt = 0, pack = 0;
    if (v < Nv) {
        int x = v % V;
        int t = v / V;
        int y = t % V;
        int z = t / V;
        const int V2 = V * V;
        float s0 = sdf[v];
        bool occ0 = s0 > 0.0f;
        bool bx = x < G, by = y < G, bz = z < G;
        int  d[7]  = {1, V, V + 1, V2, V2 + 1, V2 + V, V2 + V + 1};
        bool ok[7] = {bx, by, bx && by, bz, bx && bz, by && bz, bx && by && bz};
        u32 m = 0;
        u32 occ8 = occ0 ? 1u : 0u;
#pragma unroll
        for (int k = 0; k < 7; ++k) {
            if (ok[k]) {
                bool o1 = sdf[v + d[k]] > 0.0f;
                occ8 |= (u32)o1 << (k + 1);
                if (o1 != occ0) m |= (1u << k);
            }
        }
        vmask[v] = (u8)(m | (occ0 ? 0x80u : 0u));
        cnt = __popc(m);
        if (bx && by && bz) {
            u32 c1 = 0, c2 = 0;
#pragma unroll
            for (int w = 0; w < 6; ++w) {
                int ti = ((occ8 >> c_six[w][0]) & 1) | (((occ8 >> c_six[w][1]) & 1) << 1) |
                         (((occ8 >> c_six[w][2]) & 1) << 2) | (((occ8 >> c_six[w][3]) & 1) << 3);
                int nt = c_ntri[ti];
                c1 += (nt == 1);
                c2 += (nt == 2);
            }
            pack = c1 | (c2 << 16);
        }
    }
    int lane = threadIdx.x & 63, wid = threadIdx.x >> 6;
    u32 sc = cnt, sp = pack;
#pragma unroll
    for (int o = 32; o > 0; o >>= 1) {
        sc += __shfl_down(sc, o, 64);
        sp += __shfl_down(sp, o, 64);
    }
    __shared__ u32 wc[4], wp[4];
    if (lane == 0) { wc[wid] = sc; wp[wid] = sp; }
    __syncthreads();
    if (threadIdx.x == 0) {
        vbsums[blockIdx.x] = wc[0] + wc[1] + wc[2] + wc[3];
        cbsums[blockIdx.x] = wp[0] + wp[1] + wp[2] + wp[3];
    }
}

// ---- block 0: scan vbsums (-> totals[0]); block 1: scan cbsums->coffs -----
// 256 THREADS ONLY (round-6 lesson: launched at 1024 -> wred[wid>3] LDS OOB
// + overlapping coverage -> garbage offsets -> OOB stores -> device abort).
__global__ void k_scan_both(u32* __restrict__ vbsums, int nV,
                            u32* __restrict__ cbsums, u64* __restrict__ coffs, int nC,
                            u32* __restrict__ totals) {
    int tid = threadIdx.x;
    int lane = tid & 63, wid = tid >> 6;
    if (blockIdx.x == 0) {
        __shared__ u32 wred[4];
        __shared__ u32 s_carry;
        if (tid == 0) s_carry = 0;
        __syncthreads();
        for (int start = 0; start < nV; start += 1024) {
            int i0 = start + tid * 4;
            u32 a0 = (i0     < nV) ? vbsums[i0]     : 0u;
            u32 a1 = (i0 + 1 < nV) ? vbsums[i0 + 1] : 0u;
            u32 a2 = (i0 + 2 < nV) ? vbsums[i0 + 2] : 0u;
            u32 a3 = (i0 + 3 < nV) ? vbsums[i0 + 3] : 0u;
            u32 t1 = a0 + a1, t2 = t1 + a2, t3 = t2 + a3;
            u32 v = t3;
#pragma unroll
            for (int o = 1; o < 64; o <<= 1) {
                u32 t = __shfl_up(v, o, 64);
                if (lane >= o) v += t;
            }
            if (lane == 63) wred[wid] = v;
            __syncthreads();
            u32 wb = 0;
#pragma unroll
            for (int k = 0; k < 4; ++k)
                if (k < wid) wb += wred[k];
            u32 carry = s_carry;
            u32 eb = carry + wb + v - t3;
            if (i0     < nV) vbsums[i0]     = eb;
            if (i0 + 1 < nV) vbsums[i0 + 1] = eb + a0;
            if (i0 + 2 < nV) vbsums[i0 + 2] = eb + t1;
            if (i0 + 3 < nV) vbsums[i0 + 3] = eb + t2;
            __syncthreads();
            if (tid == 0) s_carry = carry + wred[0] + wred[1] + wred[2] + wred[3];
            __syncthreads();
        }
        if (tid == 0) totals[0] = s_carry;  // E
        return;
    }
    {
        __shared__ u64 wred[4];
        __shared__ u64 s_carry;
        if (tid == 0) s_carry = 0;
        __syncthreads();
        for (int start = 0; start < nC; start += 1024) {
            int i0 = start + tid * 4;
            u32 r0 = (i0     < nC) ? cbsums[i0]     : 0u;
            u32 r1 = (i0 + 1 < nC) ? cbsums[i0 + 1] : 0u;
            u32 r2 = (i0 + 2 < nC) ? cbsums[i0 + 2] : 0u;
            u32 r3 = (i0 + 3 < nC) ? cbsums[i0 + 3] : 0u;
            u64 a0 = (u64)(r0 & 0xFFFFu) | ((u64)(r0 >> 16) << 32);
            u64 a1 = (u64)(r1 & 0xFFFFu) | ((u64)(r1 >> 16) << 32);
            u64 a2 = (u64)(r2 & 0xFFFFu) | ((u64)(r2 >> 16) << 32);
            u64 a3 = (u64)(r3 & 0xFFFFu) | ((u64)(r3 >> 16) << 32);
            u64 t1 = a0 + a1, t2 = t1 + a2, t3 = t2 + a3;
            u64 v = t3;
#pragma unroll
            for (int o = 1; o < 64; o <<= 1) {
                u64 t = __shfl_up(v, o, 64);
                if (lane >= o) v += t;
            }
            if (lane == 63) wred[wid] = v;
            __syncthreads();
            u64 wb = 0;
#pragma unroll
            for (int k = 0; k < 4; ++k)
                if (k < wid) wb += wred[k];
            u64 carry = s_carry;
            u64 eb = carry + wb + v - t3;
            if (i0     < nC) coffs[i0]     = eb;
            if (i0 + 1 < nC) coffs[i0 + 1] = eb + a0;
            if (i0 + 2 < nC) coffs[i0 + 2] = eb + t1;
            if (i0 + 3 < nC) coffs[i0 + 3] = eb + t2;
            __syncthreads();
            if (tid == 0) s_carry = carry + wred[0] + wred[1] + wred[2] + wred[3];
            __syncthreads();
        }
        if (tid == 0) {
            u64 c = s_carry;
            totals[1] = (u32)(c & 0xFFFFFFFFull);  // Tm1
            totals[2] = (u32)(c >> 32);            // Tm2
        }
    }
}

// ---- uvs element helper (head/tail scalar path) ---------------------------
__device__ inline float uv_elem(long long e, int Nuv, double invN, double step_d,
                                float pad, float last) {
    long long p = e >> 3;
    int i = (int)((double)p * invN);
    int j = (int)(p - (long long)i * Nuv);
    if (j >= Nuv) { j -= Nuv; ++i; }
    int r = (int)(e & 7);
    int c = r >> 1;
    if ((r & 1) == 0) {
        float tx = (j == Nuv - 1) ? last : (float)((double)j * step_d);
        return tx + ((c == 1 || c == 2) ? pad : 0.0f);
    }
    float ty = (i == Nuv - 1) ? last : (float)((double)i * step_d);
    return ty + ((c >= 2) ? pad : 0.0f);
}

// ---- uvs: one uv quad (8 elements, 2x16B NT stores) per thread ------------
__global__ void k_uvs(const u32* __restrict__ totals, float* __restrict__ out,
                      int Nuv, double invN, double step_d, float pad, float last,
                      long long npts2) {
    int tid = threadIdx.x;
    u32 E = totals[0], Tm1 = totals[1], Tm2 = totals[2];
    u64 base = 3ull * E + 3ull * ((u64)Tm1 + 2ull * (u64)Tm2);
    float* uvs = out + base;
    int a = (int)((4 - (base & 3)) & 3);  // first 16B-aligned element
    long long nthr = (npts2 - a) >> 3;
    long long t = (long long)blockIdx.x * 256 + tid;
    if (t < nthr) {
        int i = (int)((double)t * invN);
        int j = (int)(t - (long long)i * Nuv);
        if (j >= Nuv) { j -= Nuv; ++i; }
        float tx  = (j == Nuv - 1) ? last : (float)((double)j * step_d);
        float ty  = (i == Nuv - 1) ? last : (float)((double)i * step_d);
        float txp = tx + pad, typ = ty + pad;
        int j1 = j + 1, i1 = i;
        if (j1 == Nuv) { j1 = 0; ++i1; }
        float tx1  = (j1 == Nuv - 1) ? last : (float)((double)j1 * step_d);
        float ty1  = (i1 == Nuv - 1) ? last : (float)((double)i1 * step_d);
        float txp1 = tx1 + pad, typ1 = ty1 + pad;
        // quad pattern: [tx,ty,txp,ty,txp,typ,tx,typ]
        f32x4 s0, s1;
        switch (a) {
            case 0:  s0 = (f32x4){tx,  ty,  txp, ty };  s1 = (f32x4){txp, typ, tx,  typ};  break;
            case 1:  s0 = (f32x4){ty,  txp, ty,  txp};  s1 = (f32x4){typ, tx,  typ, tx1};  break;
            case 2:  s0 = (f32x4){txp, ty,  txp, typ};  s1 = (f32x4){tx,  typ, tx1, ty1};  break;
            default: s0 = (f32x4){ty,  txp, typ, tx };  s1 = (f32x4){typ, tx1, ty1, txp1}; break;
        }
        long long g0 = (long long)a + 8 * t;
        __builtin_nontemporal_store(s0, (f32x4*)(uvs + g0));
        __builtin_nontemporal_store(s1, (f32x4*)(uvs + g0 + 4));
    } else if (t == nthr) {
        for (long long e = 0; e < a; ++e)
            uvs[e] = uv_elem(e, Nuv, invN, step_d, pad, last);
        for (long long e = (long long)a + 8 * nthr; e < npts2; ++e)
            uvs[e] = uv_elem(e, Nuv, invN, step_d, pad, last);
    }
}

// ---- vbase materialize + crossing-vertex interpolation (fused) ------------
__global__ void k_vbase_verts(const u8* __restrict__ vmask, const u32* __restrict__ vbsums,
                              u32* __restrict__ vbase, const float* __restrict__ sdf,
                              float* __restrict__ out, int Nv, int V, float h) {
    int v = blockIdx.x * 256 + threadIdx.x;
    u32 m = (v < Nv) ? (u32)(vmask[v] & 0x7Fu) : 0u;
    u32 cnt = __popc(m);
    int lane = threadIdx.x & 63, wid = threadIdx.x >> 6;
    u32 s = cnt;
#pragma unroll
    for (int o = 1; o < 64; o <<= 1) {
        u32 t = __shfl_up(s, o, 64);
        if (lane >= o) s += t;
    }
    __shared__ u32 wsum[4];
    if (lane == 63) wsum[wid] = s;
    __syncthreads();
    u32 wb = 0;
#pragma unroll
    for (int k = 0; k < 4; ++k)
        if (k < wid) wb += wsum[k];
    u32 base = vbsums[blockIdx.x] + wb + s - cnt;
    if (v < Nv) vbase[v] = base;
    if (!m) return;

    int x = v % V;
    int t2 = v / V;
    int y = t2 % V;
    int z = t2 / V;
    const int V2 = V * V;
    const int d[7]  = {1, V, V + 1, V2, V2 + 1, V2 + V, V2 + V + 1};
    const int dx[7] = {1, 0, 1, 0, 1, 0, 1};
    const int dy[7] = {0, 1, 1, 0, 0, 1, 1};
    const int dz[7] = {0, 0, 0, 1, 1, 1, 1};
    float px = -1.0f + x * h, py = -1.0f + y * h, pz = -1.0f + z * h;
    float s0 = sdf[v];
    u32 r = base;
#pragma unroll
    for (int k = 0; k < 7; ++k) {
        if (m & (1u << k)) {
            float s1 = sdf[v + d[k]];
            float denom = s0 - s1;
            float w0 = -s1 / denom;
            float w1 = s0 / denom;
            out[3ull * r + 0] = px * w0 + (px + dx[k] * h) * w1;
            out[3ull * r + 1] = py * w0 + (py + dy[k] * h) * w1;
            out[3ull * r + 2] = pz * w0 + (pz + dz[k] * h) * w1;
            r++;
        }
    }
}

// ---- faces + uv_idx, vertex-indexed, procedural connectivity --------------
__global__ void k_facesuv(const u8* __restrict__ vmask, const u32* __restrict__ vbase,
                          const u64* __restrict__ coffs, const u32* __restrict__ totals,
                          float* __restrict__ out, int Nv, int G, int V, long long npts2) {
    int v = blockIdx.x * 256 + threadIdx.x;
    const int V2 = V * V;
    u32 pack = 0, occ8 = 0;
    int x = 0, y = 0, z = 0;
    bool interior = false;
    if (v < Nv) {
        x = v % V;
        int t = v / V;
        y = t % V;
        z = t / V;
        interior = (x < G) && (y < G) && (z < G);
    }
    const int off[8] = {0, 1, V, V + 1, V2, V2 + 1, V2 + V, V2 + V + 1};
    if (interior) {
#pragma unroll
        for (int n = 0; n < 8; ++n) occ8 |= (u32)(vmask[v + off[n]] >> 7) << n;
        u32 c1 = 0, c2 = 0;
#pragma unroll
        for (int w = 0; w < 6; ++w) {
            int ti = ((occ8 >> c_six[w][0]) & 1) | (((occ8 >> c_six[w][1]) & 1) << 1) |
                     (((occ8 >> c_six[w][2]) & 1) << 2) | (((occ8 >> c_six[w][3]) & 1) << 3);
            int nt = c_ntri[ti];
            c1 += (nt == 1);
            c2 += (nt == 2);
        }
        pack = c1 | (c2 << 16);
    }
    int lane = threadIdx.x & 63, wid = threadIdx.x >> 6;
    u32 s = pack;
#pragma unroll
    for (int o = 1; o < 64; o <<= 1) {
        u32 t = __shfl_up(s, o, 64);
        if (lane >= o) s += t;
    }
    __shared__ u32 wsum[4];
    if (lane == 63) wsum[wid] = s;
    __syncthreads();
    u32 wb = 0;
#pragma unroll
    for (int k = 0; k < 4; ++k)
        if (k < wid) wb += wsum[k];
    u32 excl = wb + s - pack;
    if (!interior || pack == 0) return;

    u64 bo = coffs[blockIdx.x];
    u32 m1pos = (u32)(bo & 0xFFFFFFFFull) + (excl & 0xFFFFu);
    u32 m2pos = (u32)(bo >> 32) + (excl >> 16);
    u32 E = totals[0], Tm1 = totals[1], Tm2 = totals[2];
    u64 T = (u64)Tm1 + 2ull * (u64)Tm2;
    float* faces = out + 3ull * E;
    float* uvidx = out + 3ull * E + 3ull * T + (u64)npts2;
    int ci = (z * G + y) * G + x;

#pragma unroll
    for (int w = 0; w < 6; ++w) {
        int ti = ((occ8 >> c_six[w][0]) & 1) | (((occ8 >> c_six[w][1]) & 1) << 1) |
                 (((occ8 >> c_six[w][2]) & 1) << 2) | (((occ8 >> c_six[w][3]) & 1) << 3);
        int nt = c_ntri[ti];
        if (!nt) continue;
        int t = ci * 6 + w;
        for (int tri = 0; tri < nt; ++tri) {
            u64 r = (nt == 1) ? (u64)m1pos : ((u64)Tm1 + 2ull * (u64)m2pos + (u64)tri);
#pragma unroll
            for (int cidx = 0; cidx < 3; ++cidx) {
                int e = c_tri[ti][3 * tri + cidx];
                int np_ = c_six[w][(int)c_edge_p[e]];
                int nq_ = c_six[w][(int)c_edge_q[e]];
                int lo = np_ < nq_ ? np_ : nq_;
                int k = (np_ ^ nq_) - 1;  // corners form a bit-subset chain
                int lonode = v + off[lo];
                u32 vi = vbase[lonode] +
                         (u32)__popc((u32)(vmask[lonode] & 0x7Fu) & ((1u << k) - 1u));
                faces[3ull * r + cidx] = (float)vi;
            }
            uvidx[3ull * r + 0] = (float)(4 * t);
            uvidx[3ull * r + 1] = (float)(4 * t + tri + 1);
            uvidx[3ull * r + 2] = (float)(4 * t + tri + 2);
        }
        if (nt == 1) m1pos++;
        else m2pos++;
    }
}

extern "C" void kernel_launch(void* const* d_in, const int* in_sizes, int n_in,
                              void* d_out, int out_size, void* d_ws, size_t ws_size,
                              hipStream_t stream) {
    const float* sdf = (const float*)d_in[1];
    int Nv = in_sizes[1];
    int F = in_sizes[2] / 4;

    int V = 1;
    while ((long long)V * V * V < (long long)Nv) V++;
    int G = V - 1;

    long long half = (2ll * (long long)F + 1) / 2;
    int Nuv = (int)std::sqrt((double)half);
    while ((long long)Nuv * Nuv < half) Nuv++;
    while (Nuv > 1 && (long long)(Nuv - 1) * (Nuv - 1) >= half) Nuv--;

    int nbV = (Nv + 255) / 256;
    long long npts2 = 2ll * 4ll * (long long)Nuv * (long long)Nuv;

    double invN = 1.0 / (double)Nuv;
    double step_d = (1.0 - invN) / (double)(Nuv - 1);
    float pad = (float)(0.9 * invN);
    float last = (float)(1.0 - invN);

    char* ws = (char*)d_ws;
    size_t off = 0;
    auto walloc = [&](size_t bytes) -> void* {
        void* p = ws + off;
        off = (off + bytes + 255) & ~(size_t)255;
        return p;
    };
    u32* totals = (u32*)walloc(64);
    u32* vbsums = (u32*)walloc(sizeof(u32) * (size_t)nbV);
    u32* cbsums = (u32*)walloc(sizeof(u32) * (size_t)nbV);
    u64* coffs  = (u64*)walloc(sizeof(u64) * (size_t)nbV);
    u8*  vmask  = (u8*)walloc((size_t)Nv);
    u32* vbase  = (u32*)walloc(sizeof(u32) * (size_t)Nv);
    (void)ws_size;

    float* out = (float*)d_out;
    float h = 2.0f / (float)G;

    long long nthrU = npts2 / 8 + 1;  // +1 thread for head/tail scalars
    int nbU = (int)((nthrU + 255) / 256);

    hipLaunchKernelGGL(k_main, dim3(nbV), dim3(256), 0, stream, sdf, vmask, vbsums, cbsums,
                       Nv, V, G);
    hipLaunchKernelGGL(k_scan_both, dim3(2), dim3(256), 0, stream, vbsums, nbV, cbsums, coffs,
                       nbV, totals);
    hipLaunchKernelGGL(k_uvs, dim3(nbU), dim3(256), 0, stream, totals, out, Nuv, invN, step_d,
                       pad, last, npts2);
    hipLaunchKernelGGL(k_vbase_verts, dim3(nbV), dim3(256), 0, stream, vmask, vbsums, vbase,
                       sdf, out, Nv, V, h);
    hipLaunchKernelGGL(k_facesuv, dim3(nbV), dim3(256), 0, stream, vmask, vbase, coffs, totals,
                       out, Nv, G, V, npts2);
}

// Round 8
// 163.055 us; speedup vs baseline: 3.1001x; 1.4635x over previous
//
#include <hip/hip_runtime.h>
#include <cmath>

typedef unsigned int u32;
typedef unsigned long long u64;
typedef unsigned char u8;
typedef float f32x4 __attribute__((ext_vector_type(4)));

// Marching-tets tables from the reference
__constant__ signed char c_tri[16][6] = {
    {-1,-1,-1,-1,-1,-1},
    { 1, 0, 2,-1,-1,-1},
    { 4, 0, 3,-1,-1,-1},
    { 1, 4, 2, 1, 3, 4},
    { 3, 1, 5,-1,-1,-1},
    { 2, 3, 0, 2, 5, 3},
    { 1, 4, 0, 1, 5, 4},
    { 4, 2, 5,-1,-1,-1},
    { 4, 5, 2,-1,-1,-1},
    { 4, 1, 0, 4, 5, 1},
    { 3, 2, 0, 3, 5, 2},
    { 1, 3, 5,-1,-1,-1},
    { 4, 1, 2, 4, 3, 1},
    { 3, 0, 4,-1,-1,-1},
    { 2, 0, 1,-1,-1,-1},
    {-1,-1,-1,-1,-1,-1}};
__constant__ signed char c_ntri[16] = {0,1,1,2,1,2,2,1,1,2,2,1,2,1,1,0};
__constant__ signed char c_edge_p[6] = {0,0,0,1,1,2};
__constant__ signed char c_edge_q[6] = {1,2,3,2,3,3};
// 6-tet decomposition of a cube around the 0-7 diagonal (corner n: bit0=dx,bit1=dy,bit2=dz)
__constant__ u8 c_six[6][4] = {{0,5,1,7},{0,1,3,7},{0,3,2,7},{0,2,6,7},{0,6,4,7},{0,4,5,7}};

// ---- fused pass: vertex crossing mask + occ bit + cube tet counts ---------
// (verified round 7) NO grand-total atomics (round-5 lesson: same-line
// cross-XCD atomics serialized ~250us).
__global__ void k_main(const float* __restrict__ sdf, u8* __restrict__ vmask,
                       u32* __restrict__ vbsums, u32* __restrict__ cbsums,
                       int Nv, int V, int G) {
    int v = blockIdx.x * 256 + threadIdx.x;
    u32 cnt = 0, pack = 0;
    if (v < Nv) {
        int x = v % V;
        int t = v / V;
        int y = t % V;
        int z = t / V;
        const int V2 = V * V;
        float s0 = sdf[v];
        bool occ0 = s0 > 0.0f;
        bool bx = x < G, by = y < G, bz = z < G;
        int  d[7]  = {1, V, V + 1, V2, V2 + 1, V2 + V, V2 + V + 1};
        bool ok[7] = {bx, by, bx && by, bz, bx && bz, by && bz, bx && by && bz};
        u32 m = 0;
        u32 occ8 = occ0 ? 1u : 0u;
#pragma unroll
        for (int k = 0; k < 7; ++k) {
            if (ok[k]) {
                bool o1 = sdf[v + d[k]] > 0.0f;
                occ8 |= (u32)o1 << (k + 1);
                if (o1 != occ0) m |= (1u << k);
            }
        }
        vmask[v] = (u8)(m | (occ0 ? 0x80u : 0u));
        cnt = __popc(m);
        if (bx && by && bz) {
            u32 c1 = 0, c2 = 0;
#pragma unroll
            for (int w = 0; w < 6; ++w) {
                int ti = ((occ8 >> c_six[w][0]) & 1) | (((occ8 >> c_six[w][1]) & 1) << 1) |
                         (((occ8 >> c_six[w][2]) & 1) << 2) | (((occ8 >> c_six[w][3]) & 1) << 3);
                int nt = c_ntri[ti];
                c1 += (nt == 1);
                c2 += (nt == 2);
            }
            pack = c1 | (c2 << 16);
        }
    }
    int lane = threadIdx.x & 63, wid = threadIdx.x >> 6;
    u32 sc = cnt, sp = pack;
#pragma unroll
    for (int o = 32; o > 0; o >>= 1) {
        sc += __shfl_down(sc, o, 64);
        sp += __shfl_down(sp, o, 64);
    }
    __shared__ u32 wc[4], wp[4];
    if (lane == 0) { wc[wid] = sc; wp[wid] = sp; }
    __syncthreads();
    if (threadIdx.x == 0) {
        vbsums[blockIdx.x] = wc[0] + wc[1] + wc[2] + wc[3];
        cbsums[blockIdx.x] = wp[0] + wp[1] + wp[2] + wp[3];
    }
}

// ---- scans (ROUND-4 VERIFIED VERSION: 1024 threads, 1 elem/thread/iter) ---
// block 0: u32 vbsums in place -> totals[0]; block 1: cbsums -> u64 coffs
__global__ void k_scan_both(u32* __restrict__ vbsums, int nV,
                            const u32* __restrict__ cbsums, u64* __restrict__ coffs,
                            int nC, u32* __restrict__ totals) {
    int tid = threadIdx.x;
    int lane = tid & 63, wid = tid >> 6;
    if (blockIdx.x == 0) {
        __shared__ u32 wsum[16];
        __shared__ u32 carry;
        if (tid == 0) carry = 0;
        __syncthreads();
        for (int start = 0; start < nV; start += 1024) {
            int i = start + tid;
            u32 orig = (i < nV) ? vbsums[i] : 0u;
            u32 v = orig;
#pragma unroll
            for (int o = 1; o < 64; o <<= 1) {
                u32 t = __shfl_up(v, o, 64);
                if (lane >= o) v += t;
            }
            if (lane == 63) wsum[wid] = v;
            __syncthreads();
            if (wid == 0) {
                u32 w = (lane < 16) ? wsum[lane] : 0u;
#pragma unroll
                for (int o = 1; o < 16; o <<= 1) {
                    u32 t = __shfl_up(w, o, 64);
                    if (lane >= o) w += t;
                }
                if (lane < 16) wsum[lane] = w;
            }
            __syncthreads();
            u32 base = carry + (wid ? wsum[wid - 1] : 0u);
            if (i < nV) vbsums[i] = base + v - orig;
            __syncthreads();
            if (tid == 0) carry += wsum[15];
            __syncthreads();
        }
        if (tid == 0) totals[0] = carry;  // E
    } else {
        __shared__ u64 wsum[16];
        __shared__ u64 carry;
        if (tid == 0) carry = 0;
        __syncthreads();
        for (int start = 0; start < nC; start += 1024) {
            int i = start + tid;
            u32 raw = (i < nC) ? cbsums[i] : 0u;
            u64 orig = (u64)(raw & 0xFFFFu) | ((u64)(raw >> 16) << 32);
            u64 v = orig;
#pragma unroll
            for (int o = 1; o < 64; o <<= 1) {
                u64 t = __shfl_up(v, o, 64);
                if (lane >= o) v += t;
            }
            if (lane == 63) wsum[wid] = v;
            __syncthreads();
            if (wid == 0) {
                u64 w = (lane < 16) ? wsum[lane] : 0ull;
#pragma unroll
                for (int o = 1; o < 16; o <<= 1) {
                    u64 t = __shfl_up(w, o, 64);
                    if (lane >= o) w += t;
                }
                if (lane < 16) wsum[lane] = w;
            }
            __syncthreads();
            u64 base = carry + (wid ? wsum[wid - 1] : 0ull);
            if (i < nC) coffs[i] = base + v - orig;
            __syncthreads();
            if (tid == 0) carry += wsum[15];
            __syncthreads();
        }
        if (tid == 0) {
            totals[1] = (u32)(carry & 0xFFFFFFFFull);  // Tm1
            totals[2] = (u32)(carry >> 32);            // Tm2
        }
    }
}

// ---- vbase materialize + crossing-vertex interpolation (fused) ------------
__global__ void k_vbase_verts(const u8* __restrict__ vmask, const u32* __restrict__ vbsums,
                              u32* __restrict__ vbase, const float* __restrict__ sdf,
                              float* __restrict__ out, int Nv, int V, float h) {
    int v = blockIdx.x * 256 + threadIdx.x;
    u32 m = (v < Nv) ? (u32)(vmask[v] & 0x7Fu) : 0u;
    u32 cnt = __popc(m);
    int lane = threadIdx.x & 63, wid = threadIdx.x >> 6;
    u32 s = cnt;
#pragma unroll
    for (int o = 1; o < 64; o <<= 1) {
        u32 t = __shfl_up(s, o, 64);
        if (lane >= o) s += t;
    }
    __shared__ u32 wsum[4];
    if (lane == 63) wsum[wid] = s;
    __syncthreads();
    u32 wb = 0;
#pragma unroll
    for (int k = 0; k < 4; ++k)
        if (k < wid) wb += wsum[k];
    u32 base = vbsums[blockIdx.x] + wb + s - cnt;
    if (v < Nv) vbase[v] = base;
    if (!m) return;

    int x = v % V;
    int t2 = v / V;
    int y = t2 % V;
    int z = t2 / V;
    const int V2 = V * V;
    const int d[7]  = {1, V, V + 1, V2, V2 + 1, V2 + V, V2 + V + 1};
    const int dx[7] = {1, 0, 1, 0, 1, 0, 1};
    const int dy[7] = {0, 1, 1, 0, 0, 1, 1};
    const int dz[7] = {0, 0, 0, 1, 1, 1, 1};
    float px = -1.0f + x * h, py = -1.0f + y * h, pz = -1.0f + z * h;
    float s0 = sdf[v];
    u32 r = base;
#pragma unroll
    for (int k = 0; k < 7; ++k) {
        if (m & (1u << k)) {
            float s1 = sdf[v + d[k]];
            float denom = s0 - s1;
            float w0 = -s1 / denom;
            float w1 = s0 / denom;
            out[3ull * r + 0] = px * w0 + (px + dx[k] * h) * w1;
            out[3ull * r + 1] = py * w0 + (py + dy[k] * h) * w1;
            out[3ull * r + 2] = pz * w0 + (pz + dz[k] * h) * w1;
            r++;
        }
    }
}

// ---- faces + uv_idx, vertex-indexed, procedural connectivity --------------
__global__ void k_facesuv(const u8* __restrict__ vmask, const u32* __restrict__ vbase,
                          const u64* __restrict__ coffs, const u32* __restrict__ totals,
                          float* __restrict__ out, int Nv, int G, int V, long long npts2) {
    int v = blockIdx.x * 256 + threadIdx.x;
    const int V2 = V * V;
    u32 pack = 0, occ8 = 0;
    int x = 0, y = 0, z = 0;
    bool interior = false;
    if (v < Nv) {
        x = v % V;
        int t = v / V;
        y = t % V;
        z = t / V;
        interior = (x < G) && (y < G) && (z < G);
    }
    const int off[8] = {0, 1, V, V + 1, V2, V2 + 1, V2 + V, V2 + V + 1};
    if (interior) {
#pragma unroll
        for (int n = 0; n < 8; ++n) occ8 |= (u32)(vmask[v + off[n]] >> 7) << n;
        u32 c1 = 0, c2 = 0;
#pragma unroll
        for (int w = 0; w < 6; ++w) {
            int ti = ((occ8 >> c_six[w][0]) & 1) | (((occ8 >> c_six[w][1]) & 1) << 1) |
                     (((occ8 >> c_six[w][2]) & 1) << 2) | (((occ8 >> c_six[w][3]) & 1) << 3);
            int nt = c_ntri[ti];
            c1 += (nt == 1);
            c2 += (nt == 2);
        }
        pack = c1 | (c2 << 16);
    }
    int lane = threadIdx.x & 63, wid = threadIdx.x >> 6;
    u32 s = pack;
#pragma unroll
    for (int o = 1; o < 64; o <<= 1) {
        u32 t = __shfl_up(s, o, 64);
        if (lane >= o) s += t;
    }
    __shared__ u32 wsum[4];
    if (lane == 63) wsum[wid] = s;
    __syncthreads();
    u32 wb = 0;
#pragma unroll
    for (int k = 0; k < 4; ++k)
        if (k < wid) wb += wsum[k];
    u32 excl = wb + s - pack;
    if (!interior || pack == 0) return;

    u64 bo = coffs[blockIdx.x];
    u32 m1pos = (u32)(bo & 0xFFFFFFFFull) + (excl & 0xFFFFu);
    u32 m2pos = (u32)(bo >> 32) + (excl >> 16);
    u32 E = totals[0], Tm1 = totals[1], Tm2 = totals[2];
    u64 T = (u64)Tm1 + 2ull * (u64)Tm2;
    float* faces = out + 3ull * E;
    float* uvidx = out + 3ull * E + 3ull * T + (u64)npts2;
    int ci = (z * G + y) * G + x;

#pragma unroll
    for (int w = 0; w < 6; ++w) {
        int ti = ((occ8 >> c_six[w][0]) & 1) | (((occ8 >> c_six[w][1]) & 1) << 1) |
                 (((occ8 >> c_six[w][2]) & 1) << 2) | (((occ8 >> c_six[w][3]) & 1) << 3);
        int nt = c_ntri[ti];
        if (!nt) continue;
        int t = ci * 6 + w;
        for (int tri = 0; tri < nt; ++tri) {
            u64 r = (nt == 1) ? (u64)m1pos : ((u64)Tm1 + 2ull * (u64)m2pos + (u64)tri);
#pragma unroll
            for (int cidx = 0; cidx < 3; ++cidx) {
                int e = c_tri[ti][3 * tri + cidx];
                int np_ = c_six[w][(int)c_edge_p[e]];
                int nq_ = c_six[w][(int)c_edge_q[e]];
                int lo = np_ < nq_ ? np_ : nq_;
                int k = (np_ ^ nq_) - 1;  // corners form a bit-subset chain
                int lonode = v + off[lo];
                u32 vi = vbase[lonode] +
                         (u32)__popc((u32)(vmask[lonode] & 0x7Fu) & ((1u << k) - 1u));
                faces[3ull * r + cidx] = (float)vi;
            }
            uvidx[3ull * r + 0] = (float)(4 * t);
            uvidx[3ull * r + 1] = (float)(4 * t + tri + 1);
            uvidx[3ull * r + 2] = (float)(4 * t + tri + 2);
        }
        if (nt == 1) m1pos++;
        else m2pos++;
    }
}

// ---- uvs helpers (ROUND-4 VERIFIED VERSION) -------------------------------
__device__ inline float uv_elem(long long e, int Nuv, double invN, double step_d,
                                float pad, float last) {
    int p = (int)(e >> 3);
    int i = (int)((double)p * invN);
    int j = p - i * Nuv;
    if (j >= Nuv) { j -= Nuv; ++i; }
    int r = (int)(e & 7);
    int c = r >> 1;
    if ((r & 1) == 0) {
        float tx = (j == Nuv - 1) ? last : (float)((double)j * step_d);
        return tx + ((c == 1 || c == 2) ? pad : 0.0f);
    }
    float ty = (i == Nuv - 1) ? last : (float)((double)i * step_d);
    return ty + ((c >= 2) ? pad : 0.0f);
}

// ---- uvs: one 16B NT store / thread (ROUND-4 VERIFIED VERSION) ------------
__global__ void k_uvs(float* __restrict__ out, const u32* __restrict__ totals,
                      int Nuv, double invN, double step_d, float pad, float last,
                      long long npts2) {
    u32 E = totals[0], Tm1 = totals[1], Tm2 = totals[2];
    u64 base = 3ull * E + 3ull * ((u64)Tm1 + 2ull * (u64)Tm2);
    float* uvs = out + base;
    long long head = (long long)((4 - (base & 3)) & 3);
    long long nvec = (npts2 - head) >> 2;  // full 16B stores
    long long t = (long long)blockIdx.x * 256 + threadIdx.x;
    if (t < nvec) {
        long long e0 = head + 4 * t;
        int p = (int)(e0 >> 3);
        int i = (int)((double)p * invN);
        int j = p - i * Nuv;
        if (j >= Nuv) { j -= Nuv; ++i; }
        float tx = (j == Nuv - 1) ? last : (float)((double)j * step_d);
        float ty = (i == Nuv - 1) ? last : (float)((double)i * step_d);
        f32x4 vals;
        int pcur = p;
#pragma unroll
        for (int q = 0; q < 4; ++q) {
            long long e = e0 + q;
            int pe = (int)(e >> 3);
            if (pe != pcur) {
                pcur = pe;
                ++j;
                if (j == Nuv) {
                    j = 0;
                    ++i;
                    ty = (i == Nuv - 1) ? last : (float)((double)i * step_d);
                }
                tx = (j == Nuv - 1) ? last : (float)((double)j * step_d);
            }
            int r = (int)(e & 7);
            int c = r >> 1;
            float v;
            if ((r & 1) == 0) v = tx + ((c == 1 || c == 2) ? pad : 0.0f);
            else              v = ty + ((c >= 2) ? pad : 0.0f);
            vals[q] = v;
        }
        __builtin_nontemporal_store(vals, (f32x4*)(uvs + e0));
    } else if (t == nvec) {
        for (long long e = 0; e < head; ++e)
            uvs[e] = uv_elem(e, Nuv, invN, step_d, pad, last);
        for (long long e = head + 4 * nvec; e < npts2; ++e)
            uvs[e] = uv_elem(e, Nuv, invN, step_d, pad, last);
    }
}

extern "C" void kernel_launch(void* const* d_in, const int* in_sizes, int n_in,
                              void* d_out, int out_size, void* d_ws, size_t ws_size,
                              hipStream_t stream) {
    const float* sdf = (const float*)d_in[1];
    int Nv = in_sizes[1];
    int F = in_sizes[2] / 4;

    int V = 1;
    while ((long long)V * V * V < (long long)Nv) V++;
    int G = V - 1;

    long long half = (2ll * (long long)F + 1) / 2;
    int Nuv = (int)std::sqrt((double)half);
    while ((long long)Nuv * Nuv < half) Nuv++;
    while (Nuv > 1 && (long long)(Nuv - 1) * (Nuv - 1) >= half) Nuv--;

    int nbV = (Nv + 255) / 256;
    long long npts2 = 2ll * 4ll * (long long)Nuv * (long long)Nuv;

    double invN = 1.0 / (double)Nuv;
    double step_d = (1.0 - invN) / (double)(Nuv - 1);
    float pad = (float)(0.9 * invN);
    float last = (float)(1.0 - invN);

    char* ws = (char*)d_ws;
    size_t off = 0;
    auto walloc = [&](size_t bytes) -> void* {
        void* p = ws + off;
        off = (off + bytes + 255) & ~(size_t)255;
        return p;
    };
    u32* totals = (u32*)walloc(64);
    u32* vbsums = (u32*)walloc(sizeof(u32) * (size_t)nbV);
    u32* cbsums = (u32*)walloc(sizeof(u32) * (size_t)nbV);
    u64* coffs  = (u64*)walloc(sizeof(u64) * (size_t)nbV);
    u8*  vmask  = (u8*)walloc((size_t)Nv);
    u32* vbase  = (u32*)walloc(sizeof(u32) * (size_t)Nv);
    (void)ws_size;

    float* out = (float*)d_out;
    float h = 2.0f / (float)G;

    long long nthr_uvs = npts2 / 4 + 1;
    int nbU = (int)((nthr_uvs + 255) / 256);

    hipLaunchKernelGGL(k_main, dim3(nbV), dim3(256), 0, stream, sdf, vmask, vbsums, cbsums,
                       Nv, V, G);
    hipLaunchKernelGGL(k_scan_both, dim3(2), dim3(1024), 0, stream, vbsums, nbV, cbsums, coffs,
                       nbV, totals);
    hipLaunchKernelGGL(k_vbase_verts, dim3(nbV), dim3(256), 0, stream, vmask, vbsums, vbase,
                       sdf, out, Nv, V, h);
    hipLaunchKernelGGL(k_facesuv, dim3(nbV), dim3(256), 0, stream, vmask, vbase, coffs, totals,
                       out, Nv, G, V, npts2);
    hipLaunchKernelGGL(k_uvs, dim3(nbU), dim3(256), 0, stream, out, totals, Nuv, invN, step_d,
                       pad, last, npts2);
}

// Round 9
// 150.455 us; speedup vs baseline: 3.3597x; 1.0837x over previous
//
#include <hip/hip_runtime.h>
#include <cmath>

typedef unsigned int u32;
typedef unsigned long long u64;
typedef unsigned char u8;
typedef unsigned short u16;
typedef float f32x4 __attribute__((ext_vector_type(4)));

// Marching-tets tables from the reference
__constant__ signed char c_tri[16][6] = {
    {-1,-1,-1,-1,-1,-1},
    { 1, 0, 2,-1,-1,-1},
    { 4, 0, 3,-1,-1,-1},
    { 1, 4, 2, 1, 3, 4},
    { 3, 1, 5,-1,-1,-1},
    { 2, 3, 0, 2, 5, 3},
    { 1, 4, 0, 1, 5, 4},
    { 4, 2, 5,-1,-1,-1},
    { 4, 5, 2,-1,-1,-1},
    { 4, 1, 0, 4, 5, 1},
    { 3, 2, 0, 3, 5, 2},
    { 1, 3, 5,-1,-1,-1},
    { 4, 1, 2, 4, 3, 1},
    { 3, 0, 4,-1,-1,-1},
    { 2, 0, 1,-1,-1,-1},
    {-1,-1,-1,-1,-1,-1}};
__constant__ signed char c_ntri[16] = {0,1,1,2,1,2,2,1,1,2,2,1,2,1,1,0};
__constant__ signed char c_edge_p[6] = {0,0,0,1,1,2};
__constant__ signed char c_edge_q[6] = {1,2,3,2,3,3};
// 6-tet decomposition of a cube around the 0-7 diagonal (corner n: bit0=dx,bit1=dy,bit2=dz)
__constant__ u8 c_six[6][4] = {{0,5,1,7},{0,1,3,7},{0,3,2,7},{0,2,6,7},{0,6,4,7},{0,4,5,7}};

// ---- fused pass: mask + occ + cube counts + INTRA-BLOCK PREFIX (pfx16) ----
// pfx16[v] = exclusive prefix of crossing-edge counts within v's 256-chunk,
// so any later block can compute vbase[v] = vbsums[v>>8] + pfx16[v].
// NO grand-total atomics (round-5 lesson).
__global__ void k_main(const float* __restrict__ sdf, u8* __restrict__ vmask,
                       u16* __restrict__ pfx16, u32* __restrict__ vbsums,
                       u32* __restrict__ cbsums, int Nv, int V, int G) {
    int v = blockIdx.x * 256 + threadIdx.x;
    u32 cnt = 0, pack = 0;
    if (v < Nv) {
        int x = v % V;
        int t = v / V;
        int y = t % V;
        int z = t / V;
        const int V2 = V * V;
        float s0 = sdf[v];
        bool occ0 = s0 > 0.0f;
        bool bx = x < G, by = y < G, bz = z < G;
        int  d[7]  = {1, V, V + 1, V2, V2 + 1, V2 + V, V2 + V + 1};
        bool ok[7] = {bx, by, bx && by, bz, bx && bz, by && bz, bx && by && bz};
        u32 m = 0;
        u32 occ8 = occ0 ? 1u : 0u;
#pragma unroll
        for (int k = 0; k < 7; ++k) {
            if (ok[k]) {
                bool o1 = sdf[v + d[k]] > 0.0f;
                occ8 |= (u32)o1 << (k + 1);
                if (o1 != occ0) m |= (1u << k);
            }
        }
        vmask[v] = (u8)(m | (occ0 ? 0x80u : 0u));
        cnt = __popc(m);
        if (bx && by && bz) {
            u32 c1 = 0, c2 = 0;
#pragma unroll
            for (int w = 0; w < 6; ++w) {
                int ti = ((occ8 >> c_six[w][0]) & 1) | (((occ8 >> c_six[w][1]) & 1) << 1) |
                         (((occ8 >> c_six[w][2]) & 1) << 2) | (((occ8 >> c_six[w][3]) & 1) << 3);
                int nt = c_ntri[ti];
                c1 += (nt == 1);
                c2 += (nt == 2);
            }
            pack = c1 | (c2 << 16);
        }
    }
    int lane = threadIdx.x & 63, wid = threadIdx.x >> 6;
    u32 s = cnt, sp = pack;
#pragma unroll
    for (int o = 1; o < 64; o <<= 1) {
        u32 t = __shfl_up(s, o, 64);
        u32 tp = __shfl_up(sp, o, 64);
        if (lane >= o) { s += t; sp += tp; }
    }
    __shared__ u32 wsum[4], wpk[4];
    if (lane == 63) { wsum[wid] = s; wpk[wid] = sp; }
    __syncthreads();
    u32 wb = 0;
#pragma unroll
    for (int k = 0; k < 4; ++k)
        if (k < wid) wb += wsum[k];
    if (v < Nv) pfx16[v] = (u16)(wb + s - cnt);
    if (threadIdx.x == 0) {
        vbsums[blockIdx.x] = wsum[0] + wsum[1] + wsum[2] + wsum[3];
        cbsums[blockIdx.x] = wpk[0] + wpk[1] + wpk[2] + wpk[3];
    }
}

// ---- scans (ROUND-4/8 VERIFIED: 1024 threads, 1 elem/thread/iter) ---------
__global__ void k_scan_both(u32* __restrict__ vbsums, int nV,
                            const u32* __restrict__ cbsums, u64* __restrict__ coffs,
                            int nC, u32* __restrict__ totals) {
    int tid = threadIdx.x;
    int lane = tid & 63, wid = tid >> 6;
    if (blockIdx.x == 0) {
        __shared__ u32 wsum[16];
        __shared__ u32 carry;
        if (tid == 0) carry = 0;
        __syncthreads();
        for (int start = 0; start < nV; start += 1024) {
            int i = start + tid;
            u32 orig = (i < nV) ? vbsums[i] : 0u;
            u32 v = orig;
#pragma unroll
            for (int o = 1; o < 64; o <<= 1) {
                u32 t = __shfl_up(v, o, 64);
                if (lane >= o) v += t;
            }
            if (lane == 63) wsum[wid] = v;
            __syncthreads();
            if (wid == 0) {
                u32 w = (lane < 16) ? wsum[lane] : 0u;
#pragma unroll
                for (int o = 1; o < 16; o <<= 1) {
                    u32 t = __shfl_up(w, o, 64);
                    if (lane >= o) w += t;
                }
                if (lane < 16) wsum[lane] = w;
            }
            __syncthreads();
            u32 base = carry + (wid ? wsum[wid - 1] : 0u);
            if (i < nV) vbsums[i] = base + v - orig;
            __syncthreads();
            if (tid == 0) carry += wsum[15];
            __syncthreads();
        }
        if (tid == 0) totals[0] = carry;  // E
    } else {
        __shared__ u64 wsum[16];
        __shared__ u64 carry;
        if (tid == 0) carry = 0;
        __syncthreads();
        for (int start = 0; start < nC; start += 1024) {
            int i = start + tid;
            u32 raw = (i < nC) ? cbsums[i] : 0u;
            u64 orig = (u64)(raw & 0xFFFFu) | ((u64)(raw >> 16) << 32);
            u64 v = orig;
#pragma unroll
            for (int o = 1; o < 64; o <<= 1) {
                u64 t = __shfl_up(v, o, 64);
                if (lane >= o) v += t;
            }
            if (lane == 63) wsum[wid] = v;
            __syncthreads();
            if (wid == 0) {
                u64 w = (lane < 16) ? wsum[lane] : 0ull;
#pragma unroll
                for (int o = 1; o < 16; o <<= 1) {
                    u64 t = __shfl_up(w, o, 64);
                    if (lane >= o) w += t;
                }
                if (lane < 16) wsum[lane] = w;
            }
            __syncthreads();
            u64 base = carry + (wid ? wsum[wid - 1] : 0ull);
            if (i < nC) coffs[i] = base + v - orig;
            __syncthreads();
            if (tid == 0) carry += wsum[15];
            __syncthreads();
        }
        if (tid == 0) {
            totals[1] = (u32)(carry & 0xFFFFFFFFull);  // Tm1
            totals[2] = (u32)(carry >> 32);            // Tm2
        }
    }
}

// ---- uvs element helper (head/tail scalar path) ---------------------------
__device__ inline float uv_elem(long long e, int Nuv, double invN, double step_d,
                                float pad, float last) {
    int p = (int)(e >> 3);
    int i = (int)((double)p * invN);
    int j = p - i * Nuv;
    if (j >= Nuv) { j -= Nuv; ++i; }
    int r = (int)(e & 7);
    int c = r >> 1;
    if ((r & 1) == 0) {
        float tx = (j == Nuv - 1) ? last : (float)((double)j * step_d);
        return tx + ((c == 1 || c == 2) ? pad : 0.0f);
    }
    float ty = (i == Nuv - 1) ? last : (float)((double)i * step_d);
    return ty + ((c >= 2) ? pad : 0.0f);
}

// ---- TAIL: blocks [0,nbV)=faces, [nbV,2nbV)=verts, [2nbV,..)=uvs ----------
// All three parts depend only on k_main+scan outputs; no cross-part deps
// (faces derives vbase[lonode] = vbsums[lonode>>8] + pfx16[lonode]).
// Latency-bound faces/verts blocks overlap the BW-bound uvs stream.
__global__ void k_tail(const float* __restrict__ sdf, const u8* __restrict__ vmask,
                       const u16* __restrict__ pfx16, const u32* __restrict__ vbsums,
                       const u64* __restrict__ coffs, const u32* __restrict__ totals,
                       float* __restrict__ out, int Nv, int V, int G, int nbV,
                       float h, int Nuv, double invN, double step_d, float pad,
                       float last, long long npts2) {
    int tid = threadIdx.x;
    int b = blockIdx.x;
    if (b < nbV) {
        // ---------------- faces + uv_idx ----------------
        int v = b * 256 + tid;
        const int V2 = V * V;
        u32 pack = 0, occ8 = 0;
        int x = 0, y = 0, z = 0;
        bool interior = false;
        if (v < Nv) {
            x = v % V;
            int t = v / V;
            y = t % V;
            z = t / V;
            interior = (x < G) && (y < G) && (z < G);
        }
        const int off[8] = {0, 1, V, V + 1, V2, V2 + 1, V2 + V, V2 + V + 1};
        if (interior) {
#pragma unroll
            for (int n = 0; n < 8; ++n) occ8 |= (u32)(vmask[v + off[n]] >> 7) << n;
            u32 c1 = 0, c2 = 0;
#pragma unroll
            for (int w = 0; w < 6; ++w) {
                int ti = ((occ8 >> c_six[w][0]) & 1) | (((occ8 >> c_six[w][1]) & 1) << 1) |
                         (((occ8 >> c_six[w][2]) & 1) << 2) | (((occ8 >> c_six[w][3]) & 1) << 3);
                int nt = c_ntri[ti];
                c1 += (nt == 1);
                c2 += (nt == 2);
            }
            pack = c1 | (c2 << 16);
        }
        int lane = tid & 63, wid = tid >> 6;
        u32 s = pack;
#pragma unroll
        for (int o = 1; o < 64; o <<= 1) {
            u32 t = __shfl_up(s, o, 64);
            if (lane >= o) s += t;
        }
        __shared__ u32 wsum[4];
        if (lane == 63) wsum[wid] = s;
        __syncthreads();
        u32 wb = 0;
#pragma unroll
        for (int k = 0; k < 4; ++k)
            if (k < wid) wb += wsum[k];
        u32 excl = wb + s - pack;
        if (!interior || pack == 0) return;

        u64 bo = coffs[b];
        u32 m1pos = (u32)(bo & 0xFFFFFFFFull) + (excl & 0xFFFFu);
        u32 m2pos = (u32)(bo >> 32) + (excl >> 16);
        u32 E = totals[0], Tm1 = totals[1], Tm2 = totals[2];
        u64 T = (u64)Tm1 + 2ull * (u64)Tm2;
        float* faces = out + 3ull * E;
        float* uvidx = out + 3ull * E + 3ull * T + (u64)npts2;
        int ci = (z * G + y) * G + x;

#pragma unroll
        for (int w = 0; w < 6; ++w) {
            int ti = ((occ8 >> c_six[w][0]) & 1) | (((occ8 >> c_six[w][1]) & 1) << 1) |
                     (((occ8 >> c_six[w][2]) & 1) << 2) | (((occ8 >> c_six[w][3]) & 1) << 3);
            int nt = c_ntri[ti];
            if (!nt) continue;
            int t = ci * 6 + w;
            for (int tri = 0; tri < nt; ++tri) {
                u64 r = (nt == 1) ? (u64)m1pos : ((u64)Tm1 + 2ull * (u64)m2pos + (u64)tri);
#pragma unroll
                for (int cidx = 0; cidx < 3; ++cidx) {
                    int e = c_tri[ti][3 * tri + cidx];
                    int np_ = c_six[w][(int)c_edge_p[e]];
                    int nq_ = c_six[w][(int)c_edge_q[e]];
                    int lo = np_ < nq_ ? np_ : nq_;
                    int k = (np_ ^ nq_) - 1;  // corners form a bit-subset chain
                    int lonode = v + off[lo];
                    u32 vi = vbsums[lonode >> 8] + (u32)pfx16[lonode] +
                             (u32)__popc((u32)(vmask[lonode] & 0x7Fu) & ((1u << k) - 1u));
                    faces[3ull * r + cidx] = (float)vi;
                }
                uvidx[3ull * r + 0] = (float)(4 * t);
                uvidx[3ull * r + 1] = (float)(4 * t + tri + 1);
                uvidx[3ull * r + 2] = (float)(4 * t + tri + 2);
            }
            if (nt == 1) m1pos++;
            else m2pos++;
        }
        return;
    }
    if (b < 2 * nbV) {
        // ---------------- crossing-vertex interpolation ----------------
        int vb = b - nbV;
        int v = vb * 256 + tid;
        if (v >= Nv) return;
        u32 m = (u32)(vmask[v] & 0x7Fu);
        if (!m) return;
        u32 r = vbsums[vb] + (u32)pfx16[v];
        int x = v % V;
        int t2 = v / V;
        int y = t2 % V;
        int z = t2 / V;
        const int V2 = V * V;
        const int d[7]  = {1, V, V + 1, V2, V2 + 1, V2 + V, V2 + V + 1};
        const int dx[7] = {1, 0, 1, 0, 1, 0, 1};
        const int dy[7] = {0, 1, 1, 0, 0, 1, 1};
        const int dz[7] = {0, 0, 0, 1, 1, 1, 1};
        float px = -1.0f + x * h, py = -1.0f + y * h, pz = -1.0f + z * h;
        float s0 = sdf[v];
#pragma unroll
        for (int k = 0; k < 7; ++k) {
            if (m & (1u << k)) {
                float s1 = sdf[v + d[k]];
                float denom = s0 - s1;
                float w0 = -s1 / denom;
                float w1 = s0 / denom;
                out[3ull * r + 0] = px * w0 + (px + dx[k] * h) * w1;
                out[3ull * r + 1] = py * w0 + (py + dy[k] * h) * w1;
                out[3ull * r + 2] = pz * w0 + (pz + dz[k] * h) * w1;
                r++;
            }
        }
        return;
    }
    // ---------------- uvs: one 16B NT store / thread ----------------
    u32 E = totals[0], Tm1 = totals[1], Tm2 = totals[2];
    u64 base = 3ull * E + 3ull * ((u64)Tm1 + 2ull * (u64)Tm2);
    float* uvs = out + base;
    long long head = (long long)((4 - (base & 3)) & 3);
    long long nvec = (npts2 - head) >> 2;  // full 16B stores
    long long t = (long long)(b - 2 * nbV) * 256 + tid;
    if (t < nvec) {
        long long e0 = head + 4 * t;
        int p = (int)(e0 >> 3);
        int i = (int)((double)p * invN);
        int j = p - i * Nuv;
        if (j >= Nuv) { j -= Nuv; ++i; }
        float tx = (j == Nuv - 1) ? last : (float)((double)j * step_d);
        float ty = (i == Nuv - 1) ? last : (float)((double)i * step_d);
        f32x4 vals;
        int pcur = p;
#pragma unroll
        for (int q = 0; q < 4; ++q) {
            long long e = e0 + q;
            int pe = (int)(e >> 3);
            if (pe != pcur) {
                pcur = pe;
                ++j;
                if (j == Nuv) {
                    j = 0;
                    ++i;
                    ty = (i == Nuv - 1) ? last : (float)((double)i * step_d);
                }
                tx = (j == Nuv - 1) ? last : (float)((double)j * step_d);
            }
            int r = (int)(e & 7);
            int c = r >> 1;
            float vv;
            if ((r & 1) == 0) vv = tx + ((c == 1 || c == 2) ? pad : 0.0f);
            else              vv = ty + ((c >= 2) ? pad : 0.0f);
            vals[q] = vv;
        }
        __builtin_nontemporal_store(vals, (f32x4*)(uvs + e0));
    } else if (t == nvec) {
        for (long long e = 0; e < head; ++e)
            uvs[e] = uv_elem(e, Nuv, invN, step_d, pad, last);
        for (long long e = head + 4 * nvec; e < npts2; ++e)
            uvs[e] = uv_elem(e, Nuv, invN, step_d, pad, last);
    }
}

extern "C" void kernel_launch(void* const* d_in, const int* in_sizes, int n_in,
                              void* d_out, int out_size, void* d_ws, size_t ws_size,
                              hipStream_t stream) {
    const float* sdf = (const float*)d_in[1];
    int Nv = in_sizes[1];
    int F = in_sizes[2] / 4;

    int V = 1;
    while ((long long)V * V * V < (long long)Nv) V++;
    int G = V - 1;

    long long half = (2ll * (long long)F + 1) / 2;
    int Nuv = (int)std::sqrt((double)half);
    while ((long long)Nuv * Nuv < half) Nuv++;
    while (Nuv > 1 && (long long)(Nuv - 1) * (Nuv - 1) >= half) Nuv--;

    int nbV = (Nv + 255) / 256;
    long long npts2 = 2ll * 4ll * (long long)Nuv * (long long)Nuv;

    double invN = 1.0 / (double)Nuv;
    double step_d = (1.0 - invN) / (double)(Nuv - 1);
    float pad = (float)(0.9 * invN);
    float last = (float)(1.0 - invN);

    char* ws = (char*)d_ws;
    size_t off = 0;
    auto walloc = [&](size_t bytes) -> void* {
        void* p = ws + off;
        off = (off + bytes + 255) & ~(size_t)255;
        return p;
    };
    u32* totals = (u32*)walloc(64);
    u32* vbsums = (u32*)walloc(sizeof(u32) * (size_t)nbV);
    u32* cbsums = (u32*)walloc(sizeof(u32) * (size_t)nbV);
    u64* coffs  = (u64*)walloc(sizeof(u64) * (size_t)nbV);
    u8*  vmask  = (u8*)walloc((size_t)Nv);
    u16* pfx16  = (u16*)walloc(sizeof(u16) * (size_t)Nv);
    (void)ws_size;

    float* out = (float*)d_out;
    float h = 2.0f / (float)G;

    long long nthr_uvs = npts2 / 4 + 1;
    int nbU = (int)((nthr_uvs + 255) / 256);

    hipLaunchKernelGGL(k_main, dim3(nbV), dim3(256), 0, stream, sdf, vmask, pfx16, vbsums,
                       cbsums, Nv, V, G);
    hipLaunchKernelGGL(k_scan_both, dim3(2), dim3(1024), 0, stream, vbsums, nbV, cbsums, coffs,
                       nbV, totals);
    hipLaunchKernelGGL(k_tail, dim3(2 * nbV + nbU), dim3(256), 0, stream, sdf, vmask, pfx16,
                       vbsums, coffs, totals, out, Nv, V, G, nbV, h, Nuv, invN, step_d, pad,
                       last, npts2);
}

// Round 10
// 147.585 us; speedup vs baseline: 3.4250x; 1.0194x over previous
//
#include <hip/hip_runtime.h>
#include <cmath>

typedef unsigned int u32;
typedef unsigned long long u64;
typedef unsigned char u8;
typedef unsigned short u16;
typedef float f32x4 __attribute__((ext_vector_type(4)));

// Marching-tets tables from the reference
__constant__ signed char c_tri[16][6] = {
    {-1,-1,-1,-1,-1,-1},
    { 1, 0, 2,-1,-1,-1},
    { 4, 0, 3,-1,-1,-1},
    { 1, 4, 2, 1, 3, 4},
    { 3, 1, 5,-1,-1,-1},
    { 2, 3, 0, 2, 5, 3},
    { 1, 4, 0, 1, 5, 4},
    { 4, 2, 5,-1,-1,-1},
    { 4, 5, 2,-1,-1,-1},
    { 4, 1, 0, 4, 5, 1},
    { 3, 2, 0, 3, 5, 2},
    { 1, 3, 5,-1,-1,-1},
    { 4, 1, 2, 4, 3, 1},
    { 3, 0, 4,-1,-1,-1},
    { 2, 0, 1,-1,-1,-1},
    {-1,-1,-1,-1,-1,-1}};
__constant__ signed char c_ntri[16] = {0,1,1,2,1,2,2,1,1,2,2,1,2,1,1,0};
__constant__ signed char c_edge_p[6] = {0,0,0,1,1,2};
__constant__ signed char c_edge_q[6] = {1,2,3,2,3,3};
// 6-tet decomposition of a cube around the 0-7 diagonal (corner n: bit0=dx,bit1=dy,bit2=dz)
__constant__ u8 c_six[6][4] = {{0,5,1,7},{0,1,3,7},{0,3,2,7},{0,2,6,7},{0,6,4,7},{0,4,5,7}};

// ---- fused pass: mask + occ + cube counts + intra-block prefix (pfx16) ----
// (verified round 9) NO grand-total atomics (round-5 lesson).
__global__ void k_main(const float* __restrict__ sdf, u8* __restrict__ vmask,
                       u16* __restrict__ pfx16, u32* __restrict__ vbsums,
                       u32* __restrict__ cbsums, int Nv, int V, int G) {
    int v = blockIdx.x * 256 + threadIdx.x;
    u32 cnt = 0, pack = 0;
    if (v < Nv) {
        int x = v % V;
        int t = v / V;
        int y = t % V;
        int z = t / V;
        const int V2 = V * V;
        float s0 = sdf[v];
        bool occ0 = s0 > 0.0f;
        bool bx = x < G, by = y < G, bz = z < G;
        int  d[7]  = {1, V, V + 1, V2, V2 + 1, V2 + V, V2 + V + 1};
        bool ok[7] = {bx, by, bx && by, bz, bx && bz, by && bz, bx && by && bz};
        u32 m = 0;
        u32 occ8 = occ0 ? 1u : 0u;
#pragma unroll
        for (int k = 0; k < 7; ++k) {
            if (ok[k]) {
                bool o1 = sdf[v + d[k]] > 0.0f;
                occ8 |= (u32)o1 << (k + 1);
                if (o1 != occ0) m |= (1u << k);
            }
        }
        vmask[v] = (u8)(m | (occ0 ? 0x80u : 0u));
        cnt = __popc(m);
        if (bx && by && bz) {
            u32 c1 = 0, c2 = 0;
#pragma unroll
            for (int w = 0; w < 6; ++w) {
                int ti = ((occ8 >> c_six[w][0]) & 1) | (((occ8 >> c_six[w][1]) & 1) << 1) |
                         (((occ8 >> c_six[w][2]) & 1) << 2) | (((occ8 >> c_six[w][3]) & 1) << 3);
                int nt = c_ntri[ti];
                c1 += (nt == 1);
                c2 += (nt == 2);
            }
            pack = c1 | (c2 << 16);
        }
    }
    int lane = threadIdx.x & 63, wid = threadIdx.x >> 6;
    u32 s = cnt, sp = pack;
#pragma unroll
    for (int o = 1; o < 64; o <<= 1) {
        u32 t = __shfl_up(s, o, 64);
        u32 tp = __shfl_up(sp, o, 64);
        if (lane >= o) { s += t; sp += tp; }
    }
    __shared__ u32 wsum[4], wpk[4];
    if (lane == 63) { wsum[wid] = s; wpk[wid] = sp; }
    __syncthreads();
    u32 wb = 0;
#pragma unroll
    for (int k = 0; k < 4; ++k)
        if (k < wid) wb += wsum[k];
    if (v < Nv) pfx16[v] = (u16)(wb + s - cnt);
    if (threadIdx.x == 0) {
        vbsums[blockIdx.x] = wsum[0] + wsum[1] + wsum[2] + wsum[3];
        cbsums[blockIdx.x] = wpk[0] + wpk[1] + wpk[2] + wpk[3];
    }
}

// ---- scans: 1024 threads x 4 consecutive elems/thread (3 rounds for 8387) -
// block 0: u32 vbsums in place -> totals[0]; block 1: cbsums -> u64 coffs
__global__ void k_scan_both(u32* __restrict__ vbsums, int nV,
                            const u32* __restrict__ cbsums, u64* __restrict__ coffs,
                            int nC, u32* __restrict__ totals) {
    int tid = threadIdx.x;
    int lane = tid & 63, wid = tid >> 6;  // wid in [0,16)
    if (blockIdx.x == 0) {
        __shared__ u32 wsum[16];
        __shared__ u32 carry;
        if (tid == 0) carry = 0;
        __syncthreads();
        for (int start = 0; start < nV; start += 4096) {
            int i0 = start + tid * 4;
            u32 a0 = (i0     < nV) ? vbsums[i0]     : 0u;
            u32 a1 = (i0 + 1 < nV) ? vbsums[i0 + 1] : 0u;
            u32 a2 = (i0 + 2 < nV) ? vbsums[i0 + 2] : 0u;
            u32 a3 = (i0 + 3 < nV) ? vbsums[i0 + 3] : 0u;
            u32 t1 = a0 + a1, t2 = t1 + a2, t3 = t2 + a3;
            u32 v = t3;
#pragma unroll
            for (int o = 1; o < 64; o <<= 1) {
                u32 t = __shfl_up(v, o, 64);
                if (lane >= o) v += t;
            }
            if (lane == 63) wsum[wid] = v;
            __syncthreads();
            if (wid == 0) {
                u32 w = (lane < 16) ? wsum[lane] : 0u;
#pragma unroll
                for (int o = 1; o < 16; o <<= 1) {
                    u32 t = __shfl_up(w, o, 64);
                    if (lane >= o) w += t;
                }
                if (lane < 16) wsum[lane] = w;
            }
            __syncthreads();
            u32 eb = carry + (wid ? wsum[wid - 1] : 0u) + v - t3;
            if (i0     < nV) vbsums[i0]     = eb;
            if (i0 + 1 < nV) vbsums[i0 + 1] = eb + a0;
            if (i0 + 2 < nV) vbsums[i0 + 2] = eb + t1;
            if (i0 + 3 < nV) vbsums[i0 + 3] = eb + t2;
            __syncthreads();
            if (tid == 0) carry += wsum[15];
            __syncthreads();
        }
        if (tid == 0) totals[0] = carry;  // E
    } else {
        __shared__ u64 wsum[16];
        __shared__ u64 carry;
        if (tid == 0) carry = 0;
        __syncthreads();
        for (int start = 0; start < nC; start += 4096) {
            int i0 = start + tid * 4;
            u32 r0 = (i0     < nC) ? cbsums[i0]     : 0u;
            u32 r1 = (i0 + 1 < nC) ? cbsums[i0 + 1] : 0u;
            u32 r2 = (i0 + 2 < nC) ? cbsums[i0 + 2] : 0u;
            u32 r3 = (i0 + 3 < nC) ? cbsums[i0 + 3] : 0u;
            u64 a0 = (u64)(r0 & 0xFFFFu) | ((u64)(r0 >> 16) << 32);
            u64 a1 = (u64)(r1 & 0xFFFFu) | ((u64)(r1 >> 16) << 32);
            u64 a2 = (u64)(r2 & 0xFFFFu) | ((u64)(r2 >> 16) << 32);
            u64 a3 = (u64)(r3 & 0xFFFFu) | ((u64)(r3 >> 16) << 32);
            u64 t1 = a0 + a1, t2 = t1 + a2, t3 = t2 + a3;
            u64 v = t3;
#pragma unroll
            for (int o = 1; o < 64; o <<= 1) {
                u64 t = __shfl_up(v, o, 64);
                if (lane >= o) v += t;
            }
            if (lane == 63) wsum[wid] = v;
            __syncthreads();
            if (wid == 0) {
                u64 w = (lane < 16) ? wsum[lane] : 0ull;
#pragma unroll
                for (int o = 1; o < 16; o <<= 1) {
                    u64 t = __shfl_up(w, o, 64);
                    if (lane >= o) w += t;
                }
                if (lane < 16) wsum[lane] = w;
            }
            __syncthreads();
            u64 eb = carry + (wid ? wsum[wid - 1] : 0ull) + v - t3;
            if (i0     < nC) coffs[i0]     = eb;
            if (i0 + 1 < nC) coffs[i0 + 1] = eb + a0;
            if (i0 + 2 < nC) coffs[i0 + 2] = eb + t1;
            if (i0 + 3 < nC) coffs[i0 + 3] = eb + t2;
            __syncthreads();
            if (tid == 0) carry += wsum[15];
            __syncthreads();
        }
        if (tid == 0) {
            totals[1] = (u32)(carry & 0xFFFFFFFFull);  // Tm1
            totals[2] = (u32)(carry >> 32);            // Tm2
        }
    }
}

// ---- uvs element helper (head/tail scalar path) ---------------------------
__device__ inline float uv_elem(long long e, int Nuv, double invN, double step_d,
                                float pad, float last) {
    int p = (int)(e >> 3);
    int i = (int)((double)p * invN);
    int j = p - i * Nuv;
    if (j >= Nuv) { j -= Nuv; ++i; }
    int r = (int)(e & 7);
    int c = r >> 1;
    if ((r & 1) == 0) {
        float tx = (j == Nuv - 1) ? last : (float)((double)j * step_d);
        return tx + ((c == 1 || c == 2) ? pad : 0.0f);
    }
    float ty = (i == Nuv - 1) ? last : (float)((double)i * step_d);
    return ty + ((c >= 2) ? pad : 0.0f);
}

// ---- TAIL with INTERLEAVED block roles ------------------------------------
// Every 6th block index is a front (faces/verts) block; the rest stream uvs.
// This overlaps the latency-bound front work with the BW-bound uvs write
// (round-9 lesson: front-blocks-first ran serially before any uvs store).
__global__ void k_tail(const float* __restrict__ sdf, const u8* __restrict__ vmask,
                       const u16* __restrict__ pfx16, const u32* __restrict__ vbsums,
                       const u64* __restrict__ coffs, const u32* __restrict__ totals,
                       float* __restrict__ out, int Nv, int V, int G, int nbV,
                       float h, int Nuv, double invN, double step_d, float pad,
                       float last, long long npts2) {
    int tid = threadIdx.x;
    int b0 = blockIdx.x;
    int nfront = 2 * nbV;
    int fidx = -1;
    if (b0 % 6 == 0) {
        int f = b0 / 6;
        if (f < nfront) fidx = f;
    }
    if (fidx >= 0 && fidx < nbV) {
        // ---------------- faces + uv_idx (verified round-9 body) ----------
        int b = fidx;
        int v = b * 256 + tid;
        const int V2 = V * V;
        u32 pack = 0, occ8 = 0;
        int x = 0, y = 0, z = 0;
        bool interior = false;
        if (v < Nv) {
            x = v % V;
            int t = v / V;
            y = t % V;
            z = t / V;
            interior = (x < G) && (y < G) && (z < G);
        }
        const int off[8] = {0, 1, V, V + 1, V2, V2 + 1, V2 + V, V2 + V + 1};
        if (interior) {
#pragma unroll
            for (int n = 0; n < 8; ++n) occ8 |= (u32)(vmask[v + off[n]] >> 7) << n;
            u32 c1 = 0, c2 = 0;
#pragma unroll
            for (int w = 0; w < 6; ++w) {
                int ti = ((occ8 >> c_six[w][0]) & 1) | (((occ8 >> c_six[w][1]) & 1) << 1) |
                         (((occ8 >> c_six[w][2]) & 1) << 2) | (((occ8 >> c_six[w][3]) & 1) << 3);
                int nt = c_ntri[ti];
                c1 += (nt == 1);
                c2 += (nt == 2);
            }
            pack = c1 | (c2 << 16);
        }
        int lane = tid & 63, wid = tid >> 6;
        u32 s = pack;
#pragma unroll
        for (int o = 1; o < 64; o <<= 1) {
            u32 t = __shfl_up(s, o, 64);
            if (lane >= o) s += t;
        }
        __shared__ u32 wsum[4];
        if (lane == 63) wsum[wid] = s;
        __syncthreads();
        u32 wb = 0;
#pragma unroll
        for (int k = 0; k < 4; ++k)
            if (k < wid) wb += wsum[k];
        u32 excl = wb + s - pack;
        if (!interior || pack == 0) return;

        u64 bo = coffs[b];
        u32 m1pos = (u32)(bo & 0xFFFFFFFFull) + (excl & 0xFFFFu);
        u32 m2pos = (u32)(bo >> 32) + (excl >> 16);
        u32 E = totals[0], Tm1 = totals[1], Tm2 = totals[2];
        u64 T = (u64)Tm1 + 2ull * (u64)Tm2;
        float* faces = out + 3ull * E;
        float* uvidx = out + 3ull * E + 3ull * T + (u64)npts2;
        int ci = (z * G + y) * G + x;

#pragma unroll
        for (int w = 0; w < 6; ++w) {
            int ti = ((occ8 >> c_six[w][0]) & 1) | (((occ8 >> c_six[w][1]) & 1) << 1) |
                     (((occ8 >> c_six[w][2]) & 1) << 2) | (((occ8 >> c_six[w][3]) & 1) << 3);
            int nt = c_ntri[ti];
            if (!nt) continue;
            int t = ci * 6 + w;
            for (int tri = 0; tri < nt; ++tri) {
                u64 r = (nt == 1) ? (u64)m1pos : ((u64)Tm1 + 2ull * (u64)m2pos + (u64)tri);
#pragma unroll
                for (int cidx = 0; cidx < 3; ++cidx) {
                    int e = c_tri[ti][3 * tri + cidx];
                    int np_ = c_six[w][(int)c_edge_p[e]];
                    int nq_ = c_six[w][(int)c_edge_q[e]];
                    int lo = np_ < nq_ ? np_ : nq_;
                    int k = (np_ ^ nq_) - 1;  // corners form a bit-subset chain
                    int lonode = v + off[lo];
                    u32 vi = vbsums[lonode >> 8] + (u32)pfx16[lonode] +
                             (u32)__popc((u32)(vmask[lonode] & 0x7Fu) & ((1u << k) - 1u));
                    faces[3ull * r + cidx] = (float)vi;
                }
                uvidx[3ull * r + 0] = (float)(4 * t);
                uvidx[3ull * r + 1] = (float)(4 * t + tri + 1);
                uvidx[3ull * r + 2] = (float)(4 * t + tri + 2);
            }
            if (nt == 1) m1pos++;
            else m2pos++;
        }
        return;
    }
    if (fidx >= 0) {
        // ---------------- crossing-vertex interpolation (round-9 body) ----
        int vb = fidx - nbV;
        int v = vb * 256 + tid;
        if (v >= Nv) return;
        u32 m = (u32)(vmask[v] & 0x7Fu);
        if (!m) return;
        u32 r = vbsums[vb] + (u32)pfx16[v];
        int x = v % V;
        int t2 = v / V;
        int y = t2 % V;
        int z = t2 / V;
        const int V2 = V * V;
        const int d[7]  = {1, V, V + 1, V2, V2 + 1, V2 + V, V2 + V + 1};
        const int dx[7] = {1, 0, 1, 0, 1, 0, 1};
        const int dy[7] = {0, 1, 1, 0, 0, 1, 1};
        const int dz[7] = {0, 0, 0, 1, 1, 1, 1};
        float px = -1.0f + x * h, py = -1.0f + y * h, pz = -1.0f + z * h;
        float s0 = sdf[v];
#pragma unroll
        for (int k = 0; k < 7; ++k) {
            if (m & (1u << k)) {
                float s1 = sdf[v + d[k]];
                float denom = s0 - s1;
                float w0 = -s1 / denom;
                float w1 = s0 / denom;
                out[3ull * r + 0] = px * w0 + (px + dx[k] * h) * w1;
                out[3ull * r + 1] = py * w0 + (py + dy[k] * h) * w1;
                out[3ull * r + 2] = pz * w0 + (pz + dz[k] * h) * w1;
                r++;
            }
        }
        return;
    }
    // ---------------- uvs: one 16B NT store / thread (round-9 body) -------
    int uidx = b0 - min((b0 + 5) / 6, nfront);
    u32 E = totals[0], Tm1 = totals[1], Tm2 = totals[2];
    u64 base = 3ull * E + 3ull * ((u64)Tm1 + 2ull * (u64)Tm2);
    float* uvs = out + base;
    long long head = (long long)((4 - (base & 3)) & 3);
    long long nvec = (npts2 - head) >> 2;  // full 16B stores
    long long t = (long long)uidx * 256 + tid;
    if (t < nvec) {
        long long e0 = head + 4 * t;
        int p = (int)(e0 >> 3);
        int i = (int)((double)p * invN);
        int j = p - i * Nuv;
        if (j >= Nuv) { j -= Nuv; ++i; }
        float tx = (j == Nuv - 1) ? last : (float)((double)j * step_d);
        float ty = (i == Nuv - 1) ? last : (float)((double)i * step_d);
        f32x4 vals;
        int pcur = p;
#pragma unroll
        for (int q = 0; q < 4; ++q) {
            long long e = e0 + q;
            int pe = (int)(e >> 3);
            if (pe != pcur) {
                pcur = pe;
                ++j;
                if (j == Nuv) {
                    j = 0;
                    ++i;
                    ty = (i == Nuv - 1) ? last : (float)((double)i * step_d);
                }
                tx = (j == Nuv - 1) ? last : (float)((double)j * step_d);
            }
            int r = (int)(e & 7);
            int c = r >> 1;
            float vv;
            if ((r & 1) == 0) vv = tx + ((c == 1 || c == 2) ? pad : 0.0f);
            else              vv = ty + ((c >= 2) ? pad : 0.0f);
            vals[q] = vv;
        }
        __builtin_nontemporal_store(vals, (f32x4*)(uvs + e0));
    } else if (t == nvec) {
        for (long long e = 0; e < head; ++e)
            uvs[e] = uv_elem(e, Nuv, invN, step_d, pad, last);
        for (long long e = head + 4 * nvec; e < npts2; ++e)
            uvs[e] = uv_elem(e, Nuv, invN, step_d, pad, last);
    }
}

extern "C" void kernel_launch(void* const* d_in, const int* in_sizes, int n_in,
                              void* d_out, int out_size, void* d_ws, size_t ws_size,
                              hipStream_t stream) {
    const float* sdf = (const float*)d_in[1];
    int Nv = in_sizes[1];
    int F = in_sizes[2] / 4;

    int V = 1;
    while ((long long)V * V * V < (long long)Nv) V++;
    int G = V - 1;

    long long half = (2ll * (long long)F + 1) / 2;
    int Nuv = (int)std::sqrt((double)half);
    while ((long long)Nuv * Nuv < half) Nuv++;
    while (Nuv > 1 && (long long)(Nuv - 1) * (Nuv - 1) >= half) Nuv--;

    int nbV = (Nv + 255) / 256;
    long long npts2 = 2ll * 4ll * (long long)Nuv * (long long)Nuv;

    double invN = 1.0 / (double)Nuv;
    double step_d = (1.0 - invN) / (double)(Nuv - 1);
    float pad = (float)(0.9 * invN);
    float last = (float)(1.0 - invN);

    char* ws = (char*)d_ws;
    size_t off = 0;
    auto walloc = [&](size_t bytes) -> void* {
        void* p = ws + off;
        off = (off + bytes + 255) & ~(size_t)255;
        return p;
    };
    u32* totals = (u32*)walloc(64);
    u32* vbsums = (u32*)walloc(sizeof(u32) * (size_t)nbV);
    u32* cbsums = (u32*)walloc(sizeof(u32) * (size_t)nbV);
    u64* coffs  = (u64*)walloc(sizeof(u64) * (size_t)nbV);
    u8*  vmask  = (u8*)walloc((size_t)Nv);
    u16* pfx16  = (u16*)walloc(sizeof(u16) * (size_t)Nv);
    (void)ws_size;

    float* out = (float*)d_out;
    float h = 2.0f / (float)G;

    long long nthr_uvs = npts2 / 4 + 1;
    int nbU = (int)((nthr_uvs + 255) / 256);
    int nfront = 2 * nbV;
    int nbTail = nbU + nfront;  // every 6th block is a front block (all fit:
                                // 6*(nfront-1) < nbTail for this problem size)

    hipLaunchKernelGGL(k_main, dim3(nbV), dim3(256), 0, stream, sdf, vmask, pfx16, vbsums,
                       cbsums, Nv, V, G);
    hipLaunchKernelGGL(k_scan_both, dim3(2), dim3(1024), 0, stream, vbsums, nbV, cbsums, coffs,
                       nbV, totals);
    hipLaunchKernelGGL(k_tail, dim3(nbTail), dim3(256), 0, stream, sdf, vmask, pfx16,
                       vbsums, coffs, totals, out, Nv, V, G, nbV, h, Nuv, invN, step_d, pad,
                       last, npts2);
}